// Round 1
// baseline (826.720 us; speedup 1.0000x reference)
//
#include <hip/hip_runtime.h>
#include <math.h>

// ---------------------------------------------------------------------------
// GCN 2-layer forward on MI355X (fp32 baseline).
// out = sigmoid( GCNConv( relu( GCNConv(x) ) ) ), PyG order: h = x@W first,
// then normalized scatter-add over edges (+self-loops), then +bias.
// ---------------------------------------------------------------------------

__global__ __launch_bounds__(256) void k_deg_init(float* __restrict__ deg, int n) {
    int i = blockIdx.x * 256 + threadIdx.x;
    if (i < n) deg[i] = 1.0f;  // self-loop weight
}

__global__ __launch_bounds__(256) void k_deg_acc(float* __restrict__ deg,
                                                 const int* __restrict__ dst,
                                                 const float* __restrict__ ew, int e) {
    int i = blockIdx.x * 256 + threadIdx.x;
    if (i < e) atomicAdd(&deg[dst[i]], ew[i]);
}

__global__ __launch_bounds__(256) void k_dinv(float* __restrict__ deg, int n) {
    int i = blockIdx.x * 256 + threadIdx.x;
    if (i < n) deg[i] = rsqrtf(deg[i]);  // deg >= 1 always
}

// ---------------------------------------------------------------------------
// GEMM: H[n x 128] = X[n x 128] @ W[128 x 128]  (fp32, vector ALU)
// Block: 128 threads, 64 rows x 64 cols per block (grid.y = 2 col halves).
// LDS: W half 32 KB + swizzled X tile 32 KB = 64 KB.
// Each thread: 4 rows x 8 cols, float4 LDS reads, k unrolled by 4.
// ---------------------------------------------------------------------------
__global__ __launch_bounds__(128) void k_gemm(const float* __restrict__ X,
                                              const float* __restrict__ W,
                                              float* __restrict__ H, int n) {
    __shared__ float sW[128 * 64];
    __shared__ float sX[64 * 128];
    const int t = threadIdx.x;
    const int row0 = blockIdx.x * 64;
    const int col0 = blockIdx.y * 64;

    // Stage W columns [col0, col0+64): 128 k x 16 float4
    for (int i = t; i < 128 * 16; i += 128) {
        int k = i >> 4, c4 = i & 15;
        float4 v = *(const float4*)(W + k * 128 + col0 + c4 * 4);
        *(float4*)(sW + k * 64 + c4 * 4) = v;
    }
    // Stage X rows [row0, row0+64) with XOR swizzle to kill bank conflicts
    for (int i = t; i < 64 * 32; i += 128) {
        int r = i >> 5, c4 = i & 31;
        int gr = row0 + r;
        float4 v = make_float4(0.f, 0.f, 0.f, 0.f);
        if (gr < n) v = *(const float4*)(X + (size_t)gr * 128 + c4 * 4);
        int sw = (r & 7) << 2;
        *(float4*)(sX + r * 128 + ((c4 * 4) ^ sw)) = v;
    }
    __syncthreads();

    const int tx = t & 7;    // col group: cols tx*8 .. tx*8+7
    const int ty = t >> 3;   // 0..15: rows ty, ty+16, ty+32, ty+48
    float acc[4][8] = {};

    for (int k = 0; k < 128; k += 4) {
        float xk[4][4];
        #pragma unroll
        for (int r = 0; r < 4; ++r) {
            int row = ty + r * 16;
            int sw = (row & 7) << 2;
            float4 v = *(const float4*)(sX + row * 128 + (k ^ sw));
            xk[r][0] = v.x; xk[r][1] = v.y; xk[r][2] = v.z; xk[r][3] = v.w;
        }
        #pragma unroll
        for (int kk = 0; kk < 4; ++kk) {
            const float* wr = sW + (k + kk) * 64 + tx * 8;
            float4 wa = *(const float4*)(wr);
            float4 wb = *(const float4*)(wr + 4);
            float wv[8] = {wa.x, wa.y, wa.z, wa.w, wb.x, wb.y, wb.z, wb.w};
            #pragma unroll
            for (int r = 0; r < 4; ++r) {
                float xs = xk[r][kk];
                #pragma unroll
                for (int c = 0; c < 8; ++c) acc[r][c] += xs * wv[c];
            }
        }
    }

    #pragma unroll
    for (int r = 0; r < 4; ++r) {
        int gr = row0 + ty + r * 16;
        if (gr < n) {
            float* o = H + (size_t)gr * 128 + col0 + tx * 8;
            *(float4*)(o)     = make_float4(acc[r][0], acc[r][1], acc[r][2], acc[r][3]);
            *(float4*)(o + 4) = make_float4(acc[r][4], acc[r][5], acc[r][6], acc[r][7]);
        }
    }
}

// ---------------------------------------------------------------------------
// Scatter aggregation: out[dst] += h[src] * (dinv[src]*ew*dinv[dst])
// Slots [0,E) are edges, [E, E+N) are self-loops (ew=1).
// 128 threads per slot (one per feature), 2 slots per 256-thread block.
// ---------------------------------------------------------------------------
__global__ __launch_bounds__(256) void k_scatter(const float* __restrict__ H,
                                                 const int* __restrict__ src,
                                                 const int* __restrict__ dst,
                                                 const float* __restrict__ ew,
                                                 const float* __restrict__ dinv,
                                                 float* __restrict__ out, int E, int N) {
    int slot = blockIdx.x * 2 + (threadIdx.x >> 7);
    int j = threadIdx.x & 127;
    if (slot < E) {
        int s = src[slot], d = dst[slot];
        float nrm = dinv[s] * ew[slot] * dinv[d];
        atomicAdd(&out[(size_t)d * 128 + j], H[(size_t)s * 128 + j] * nrm);
    } else if (slot < E + N) {
        int nd = slot - E;
        float di = dinv[nd];
        atomicAdd(&out[(size_t)nd * 128 + j], H[(size_t)nd * 128 + j] * (di * di));
    }
}

__global__ __launch_bounds__(256) void k_bias_relu(float4* __restrict__ io,
                                                   const float* __restrict__ b, int n4) {
    int i = blockIdx.x * 256 + threadIdx.x;
    if (i >= n4) return;
    int j = (i & 31) * 4;  // 32 float4 per 128-feature row
    float4 v = io[i];
    v.x = fmaxf(v.x + b[j], 0.f);
    v.y = fmaxf(v.y + b[j + 1], 0.f);
    v.z = fmaxf(v.z + b[j + 2], 0.f);
    v.w = fmaxf(v.w + b[j + 3], 0.f);
    io[i] = v;
}

__global__ __launch_bounds__(256) void k_bias_sigmoid(float4* __restrict__ io,
                                                      const float* __restrict__ b, int n4) {
    int i = blockIdx.x * 256 + threadIdx.x;
    if (i >= n4) return;
    int j = (i & 31) * 4;
    float4 v = io[i];
    v.x = 1.f / (1.f + expf(-(v.x + b[j])));
    v.y = 1.f / (1.f + expf(-(v.y + b[j + 1])));
    v.z = 1.f / (1.f + expf(-(v.z + b[j + 2])));
    v.w = 1.f / (1.f + expf(-(v.w + b[j + 3])));
    io[i] = v;
}

extern "C" void kernel_launch(void* const* d_in, const int* in_sizes, int n_in,
                              void* d_out, int out_size, void* d_ws, size_t ws_size,
                              hipStream_t stream) {
    const float* x  = (const float*)d_in[0];
    const int*   ei = (const int*)d_in[1];
    const float* ew = (const float*)d_in[2];
    const float* W1 = (const float*)d_in[3];
    const float* b1 = (const float*)d_in[4];
    const float* W2 = (const float*)d_in[5];
    const float* b2 = (const float*)d_in[6];

    const int N = in_sizes[0] / 128;
    const int E = in_sizes[2];
    const int* src = ei;          // edge_index[0]
    const int* dst = ei + E;      // edge_index[1]
    float* out = (float*)d_out;

    // Workspace layout: dinv [N floats] | h [N*128 floats]
    float* dinv = (float*)d_ws;
    float* h = (float*)((char*)d_ws + (((size_t)N * 4 + 255) & ~(size_t)255));

    const int nbN = (N + 255) / 256;
    const int nbE = (E + 255) / 256;
    const int sgrid = (E + N + 1) / 2;
    const int nbF = (N * 32 + 255) / 256;  // N*128/4 float4s
    dim3 ggrid((N + 63) / 64, 2);
    const size_t outBytes = (size_t)N * 128 * sizeof(float);

    // Degree + normalization (shared by both layers)
    k_deg_init<<<nbN, 256, 0, stream>>>(dinv, N);
    k_deg_acc<<<nbE, 256, 0, stream>>>(dinv, dst, ew, E);
    k_dinv<<<nbN, 256, 0, stream>>>(dinv, N);

    // Layer 1: h = x@W1 ; out = scatter(h) ; out = relu(out + b1)
    k_gemm<<<ggrid, 128, 0, stream>>>(x, W1, h, N);
    hipMemsetAsync(out, 0, outBytes, stream);
    k_scatter<<<sgrid, 256, 0, stream>>>(h, src, dst, ew, dinv, out, E, N);
    k_bias_relu<<<nbF, 256, 0, stream>>>((float4*)out, b1, N * 32);

    // Layer 2: h = out@W2 ; out = scatter(h) ; out = sigmoid(out + b2)
    k_gemm<<<ggrid, 128, 0, stream>>>(out, W2, h, N);
    hipMemsetAsync(out, 0, outBytes, stream);
    k_scatter<<<sgrid, 256, 0, stream>>>(h, src, dst, ew, dinv, out, E, N);
    k_bias_sigmoid<<<nbF, 256, 0, stream>>>((float4*)out, b2, N * 32);
}

// Round 2
// 476.203 us; speedup vs baseline: 1.7361x; 1.7361x over previous
//
#include <hip/hip_runtime.h>
#include <math.h>

// ---------------------------------------------------------------------------
// GCN 2-layer forward on MI355X (fp32).
// Round 2: atomic scatter -> CSR gather. Build dst-CSR once per call
// (histogram + single-block scan + fill with (src,norm) float2 pairs), then
// one 64-lane wave per node accumulates incoming messages in registers and
// writes its row once, fusing bias + activation. Removes the 2x333 MB of
// device-scope atomic write traffic that dominated Round 1 (275 us/layer).
// ---------------------------------------------------------------------------

__global__ __launch_bounds__(256) void k_deg_init(float* __restrict__ deg, int n) {
    int i = blockIdx.x * 256 + threadIdx.x;
    if (i < n) deg[i] = 1.0f;  // self-loop weight
}

// deg[dst] += ew  and  cnt[dst] += 1  in one pass over edges
__global__ __launch_bounds__(256) void k_hist(const int* __restrict__ dst,
                                              const float* __restrict__ ew,
                                              float* __restrict__ deg,
                                              int* __restrict__ cnt, int e) {
    int i = blockIdx.x * 256 + threadIdx.x;
    if (i < e) {
        int d = dst[i];
        atomicAdd(&deg[d], ew[i]);
        atomicAdd(&cnt[d], 1);
    }
}

__global__ __launch_bounds__(256) void k_dinv(float* __restrict__ deg, int n) {
    int i = blockIdx.x * 256 + threadIdx.x;
    if (i < n) deg[i] = rsqrtf(deg[i]);  // deg >= 1 always (self-loop)
}

// In-place exclusive scan over cnt[0..n), single 1024-thread block.
__global__ __launch_bounds__(1024) void k_scan(int* __restrict__ cnt, int n) {
    __shared__ int sums[1024];
    const int t = threadIdx.x;
    const int C = (n + 1023) / 1024;
    const int lo = t * C;
    const int hi = min(lo + C, n);
    int s = 0;
    for (int i = lo; i < hi; ++i) s += cnt[i];
    sums[t] = s;
    __syncthreads();
    for (int off = 1; off < 1024; off <<= 1) {
        int v = (t >= off) ? sums[t - off] : 0;
        __syncthreads();
        sums[t] += v;
        __syncthreads();
    }
    int base = (t == 0) ? 0 : sums[t - 1];
    for (int i = lo; i < hi; ++i) {
        int c = cnt[i];
        cnt[i] = base;
        base += c;
    }
}

// Fill CSR: csr[pos] = (src, dinv[src]*ew*dinv[dst]). Uses rowptr as cursor;
// after this kernel rowptr[d] == end offset of node d (start = rowptr[d-1]).
__global__ __launch_bounds__(256) void k_fill(const int* __restrict__ src,
                                              const int* __restrict__ dst,
                                              const float* __restrict__ ew,
                                              const float* __restrict__ dinv,
                                              int* __restrict__ rowptr,
                                              float2* __restrict__ csr, int e) {
    int i = blockIdx.x * 256 + threadIdx.x;
    if (i < e) {
        int s = src[i], d = dst[i];
        float nrm = dinv[s] * ew[i] * dinv[d];
        int pos = atomicAdd(&rowptr[d], 1);
        csr[pos] = make_float2(__int_as_float(s), nrm);
    }
}

// ---------------------------------------------------------------------------
// GEMM: H[n x 128] = X[n x 128] @ W[128 x 128]  (fp32, vector ALU)
// ---------------------------------------------------------------------------
__global__ __launch_bounds__(128) void k_gemm(const float* __restrict__ X,
                                              const float* __restrict__ W,
                                              float* __restrict__ H, int n) {
    __shared__ float sW[128 * 64];
    __shared__ float sX[64 * 128];
    const int t = threadIdx.x;
    const int row0 = blockIdx.x * 64;
    const int col0 = blockIdx.y * 64;

    for (int i = t; i < 128 * 16; i += 128) {
        int k = i >> 4, c4 = i & 15;
        float4 v = *(const float4*)(W + k * 128 + col0 + c4 * 4);
        *(float4*)(sW + k * 64 + c4 * 4) = v;
    }
    for (int i = t; i < 64 * 32; i += 128) {
        int r = i >> 5, c4 = i & 31;
        int gr = row0 + r;
        float4 v = make_float4(0.f, 0.f, 0.f, 0.f);
        if (gr < n) v = *(const float4*)(X + (size_t)gr * 128 + c4 * 4);
        int sw = (r & 7) << 2;
        *(float4*)(sX + r * 128 + ((c4 * 4) ^ sw)) = v;
    }
    __syncthreads();

    const int tx = t & 7;
    const int ty = t >> 3;
    float acc[4][8] = {};

    for (int k = 0; k < 128; k += 4) {
        float xk[4][4];
        #pragma unroll
        for (int r = 0; r < 4; ++r) {
            int row = ty + r * 16;
            int sw = (row & 7) << 2;
            float4 v = *(const float4*)(sX + row * 128 + (k ^ sw));
            xk[r][0] = v.x; xk[r][1] = v.y; xk[r][2] = v.z; xk[r][3] = v.w;
        }
        #pragma unroll
        for (int kk = 0; kk < 4; ++kk) {
            const float* wr = sW + (k + kk) * 64 + tx * 8;
            float4 wa = *(const float4*)(wr);
            float4 wb = *(const float4*)(wr + 4);
            float wv[8] = {wa.x, wa.y, wa.z, wa.w, wb.x, wb.y, wb.z, wb.w};
            #pragma unroll
            for (int r = 0; r < 4; ++r) {
                float xs = xk[r][kk];
                #pragma unroll
                for (int c = 0; c < 8; ++c) acc[r][c] += xs * wv[c];
            }
        }
    }

    #pragma unroll
    for (int r = 0; r < 4; ++r) {
        int gr = row0 + ty + r * 16;
        if (gr < n) {
            float* o = H + (size_t)gr * 128 + col0 + tx * 8;
            *(float4*)(o)     = make_float4(acc[r][0], acc[r][1], acc[r][2], acc[r][3]);
            *(float4*)(o + 4) = make_float4(acc[r][4], acc[r][5], acc[r][6], acc[r][7]);
        }
    }
}

// ---------------------------------------------------------------------------
// CSR gather + bias + activation. One 64-lane wave per node, 2 features
// (float2) per lane. ACT: 0 = relu, 1 = sigmoid.
// ---------------------------------------------------------------------------
template <int ACT>
__global__ __launch_bounds__(128) void k_gather(const float2* __restrict__ H2,
                                                const float2* __restrict__ csr,
                                                const int* __restrict__ endp,
                                                const float* __restrict__ dinv,
                                                const float* __restrict__ bias,
                                                float2* __restrict__ out2, int N) {
    int node = blockIdx.x * 2 + (threadIdx.x >> 6);
    if (node >= N) return;
    const int lane = threadIdx.x & 63;
    const int start = (node == 0) ? 0 : endp[node - 1];
    const int end = endp[node];

    // self-loop: ew=1, norm = dinv[node]^2
    float di = dinv[node];
    float2 hv = H2[(size_t)node * 64 + lane];
    float2 acc = make_float2(hv.x * di * di, hv.y * di * di);

    int k = start;
    for (; k + 1 < end; k += 2) {  // unroll x2: two independent row loads in flight
        float2 c0 = csr[k], c1 = csr[k + 1];
        int s0 = __float_as_int(c0.x), s1 = __float_as_int(c1.x);
        float2 h0 = H2[(size_t)s0 * 64 + lane];
        float2 h1 = H2[(size_t)s1 * 64 + lane];
        acc.x += h0.x * c0.y + h1.x * c1.y;
        acc.y += h0.y * c0.y + h1.y * c1.y;
    }
    if (k < end) {
        float2 c0 = csr[k];
        int s0 = __float_as_int(c0.x);
        float2 h0 = H2[(size_t)s0 * 64 + lane];
        acc.x += h0.x * c0.y;
        acc.y += h0.y * c0.y;
    }

    int j = lane * 2;
    acc.x += bias[j];
    acc.y += bias[j + 1];
    if (ACT == 0) {
        acc.x = fmaxf(acc.x, 0.f);
        acc.y = fmaxf(acc.y, 0.f);
    } else {
        acc.x = 1.f / (1.f + expf(-acc.x));
        acc.y = 1.f / (1.f + expf(-acc.y));
    }
    out2[(size_t)node * 64 + lane] = acc;
}

extern "C" void kernel_launch(void* const* d_in, const int* in_sizes, int n_in,
                              void* d_out, int out_size, void* d_ws, size_t ws_size,
                              hipStream_t stream) {
    const float* x  = (const float*)d_in[0];
    const int*   ei = (const int*)d_in[1];
    const float* ew = (const float*)d_in[2];
    const float* W1 = (const float*)d_in[3];
    const float* b1 = (const float*)d_in[4];
    const float* W2 = (const float*)d_in[5];
    const float* b2 = (const float*)d_in[6];

    const int N = in_sizes[0] / 128;
    const int E = in_sizes[2];
    const int* src = ei;
    const int* dst = ei + E;
    float* out = (float*)d_out;

    // Workspace layout (256B-aligned slabs):
    //   dinv [N f32] | rowptr [N+1 i32] | csr [E float2] | h [N*128 f32]
    auto align = [](size_t v) { return (v + 255) & ~(size_t)255; };
    char* p = (char*)d_ws;
    float*  dinv   = (float*)p;            p += align((size_t)N * 4);
    int*    rowptr = (int*)p;              p += align((size_t)(N + 1) * 4);
    float2* csr    = (float2*)p;           p += align((size_t)E * 8);
    float*  h      = (float*)p;

    const int nbN = (N + 255) / 256;
    const int nbE = (E + 255) / 256;
    dim3 ggrid((N + 63) / 64, 2);

    // --- CSR + normalization build (shared by both layers) ---
    hipMemsetAsync(rowptr, 0, (size_t)(N + 1) * sizeof(int), stream);
    k_deg_init<<<nbN, 256, 0, stream>>>(dinv, N);
    k_hist<<<nbE, 256, 0, stream>>>(dst, ew, dinv, rowptr, E);
    k_dinv<<<nbN, 256, 0, stream>>>(dinv, N);
    k_scan<<<1, 1024, 0, stream>>>(rowptr, N + 1);
    k_fill<<<nbE, 256, 0, stream>>>(src, dst, ew, dinv, rowptr, csr, E);

    // --- Layer 1: h = x@W1 ; out = relu(gather(h) + b1) ---
    k_gemm<<<ggrid, 128, 0, stream>>>(x, W1, h, N);
    k_gather<0><<<(N + 1) / 2, 128, 0, stream>>>((const float2*)h, csr, rowptr,
                                                 dinv, b1, (float2*)out, N);

    // --- Layer 2: h = out@W2 ; out = sigmoid(gather(h) + b2) ---
    k_gemm<<<ggrid, 128, 0, stream>>>(out, W2, h, N);
    k_gather<1><<<(N + 1) / 2, 128, 0, stream>>>((const float2*)h, csr, rowptr,
                                                 dinv, b2, (float2*)out, N);
}

// Round 3
// 401.189 us; speedup vs baseline: 2.0607x; 1.1870x over previous
//
#include <hip/hip_runtime.h>
#include <math.h>

// ---------------------------------------------------------------------------
// GCN 2-layer forward on MI355X (fp32).
// Round 3: (a) single-block scan (77 us, 1 CU busy) -> hierarchical 3-pass
// scan (~8 us); (b) gather inner loop unroll x2 -> x4 for more row loads in
// flight.
// ---------------------------------------------------------------------------

__global__ __launch_bounds__(256) void k_deg_init(float* __restrict__ deg, int n) {
    int i = blockIdx.x * 256 + threadIdx.x;
    if (i < n) deg[i] = 1.0f;  // self-loop weight
}

// deg[dst] += ew  and  cnt[dst] += 1  in one pass over edges
__global__ __launch_bounds__(256) void k_hist(const int* __restrict__ dst,
                                              const float* __restrict__ ew,
                                              float* __restrict__ deg,
                                              int* __restrict__ cnt, int e) {
    int i = blockIdx.x * 256 + threadIdx.x;
    if (i < e) {
        int d = dst[i];
        atomicAdd(&deg[d], ew[i]);
        atomicAdd(&cnt[d], 1);
    }
}

__global__ __launch_bounds__(256) void k_dinv(float* __restrict__ deg, int n) {
    int i = blockIdx.x * 256 + threadIdx.x;
    if (i < n) deg[i] = rsqrtf(deg[i]);  // deg >= 1 always (self-loop)
}

// ---------------------------------------------------------------------------
// Hierarchical exclusive scan: out[i] = sum(in[0..i)).
// Pass 1: per-1024-chunk local exclusive scan + chunk total.
// Pass 2: single small block scans the <=1024 chunk totals (exclusive).
// Pass 3: add scanned chunk offset to every element.
// ---------------------------------------------------------------------------
__global__ __launch_bounds__(256) void k_scan1(const int* __restrict__ in,
                                               int* __restrict__ out,
                                               int* __restrict__ sums, int n) {
    __shared__ int s[256];
    const int t = threadIdx.x;
    const int base = blockIdx.x * 1024 + t * 4;
    int v0 = 0, v1 = 0, v2 = 0, v3 = 0;
    if (base + 0 < n) v0 = in[base + 0];
    if (base + 1 < n) v1 = in[base + 1];
    if (base + 2 < n) v2 = in[base + 2];
    if (base + 3 < n) v3 = in[base + 3];
    s[t] = v0 + v1 + v2 + v3;
    __syncthreads();
    #pragma unroll
    for (int off = 1; off < 256; off <<= 1) {
        int x = (t >= off) ? s[t - off] : 0;
        __syncthreads();
        s[t] += x;
        __syncthreads();
    }
    if (t == 255) sums[blockIdx.x] = s[255];
    int e = (t == 0) ? 0 : s[t - 1];
    if (base + 0 < n) out[base + 0] = e;
    if (base + 1 < n) out[base + 1] = e + v0;
    if (base + 2 < n) out[base + 2] = e + v0 + v1;
    if (base + 3 < n) out[base + 3] = e + v0 + v1 + v2;
}

__global__ __launch_bounds__(1024) void k_scan2(int* __restrict__ sums, int g) {
    __shared__ int s[1024];
    const int t = threadIdx.x;
    s[t] = (t < g) ? sums[t] : 0;
    __syncthreads();
    for (int off = 1; off < 1024; off <<= 1) {
        int x = (t >= off) ? s[t - off] : 0;
        __syncthreads();
        s[t] += x;
        __syncthreads();
    }
    if (t < g) sums[t] = (t == 0) ? 0 : s[t - 1];  // exclusive
}

__global__ __launch_bounds__(256) void k_scan3(int* __restrict__ out,
                                               const int* __restrict__ sums, int n) {
    const int base = blockIdx.x * 1024 + threadIdx.x * 4;
    const int add = sums[blockIdx.x];
    #pragma unroll
    for (int u = 0; u < 4; ++u)
        if (base + u < n) out[base + u] += add;
}

// Fill CSR: csr[pos] = (src, dinv[src]*ew*dinv[dst]). Uses rowptr as cursor;
// after this kernel rowptr[d] == end offset of node d (start = rowptr[d-1]).
__global__ __launch_bounds__(256) void k_fill(const int* __restrict__ src,
                                              const int* __restrict__ dst,
                                              const float* __restrict__ ew,
                                              const float* __restrict__ dinv,
                                              int* __restrict__ rowptr,
                                              float2* __restrict__ csr, int e) {
    int i = blockIdx.x * 256 + threadIdx.x;
    if (i < e) {
        int s = src[i], d = dst[i];
        float nrm = dinv[s] * ew[i] * dinv[d];
        int pos = atomicAdd(&rowptr[d], 1);
        csr[pos] = make_float2(__int_as_float(s), nrm);
    }
}

// ---------------------------------------------------------------------------
// GEMM: H[n x 128] = X[n x 128] @ W[128 x 128]  (fp32, vector ALU)
// ---------------------------------------------------------------------------
__global__ __launch_bounds__(128) void k_gemm(const float* __restrict__ X,
                                              const float* __restrict__ W,
                                              float* __restrict__ H, int n) {
    __shared__ float sW[128 * 64];
    __shared__ float sX[64 * 128];
    const int t = threadIdx.x;
    const int row0 = blockIdx.x * 64;
    const int col0 = blockIdx.y * 64;

    for (int i = t; i < 128 * 16; i += 128) {
        int k = i >> 4, c4 = i & 15;
        float4 v = *(const float4*)(W + k * 128 + col0 + c4 * 4);
        *(float4*)(sW + k * 64 + c4 * 4) = v;
    }
    for (int i = t; i < 64 * 32; i += 128) {
        int r = i >> 5, c4 = i & 31;
        int gr = row0 + r;
        float4 v = make_float4(0.f, 0.f, 0.f, 0.f);
        if (gr < n) v = *(const float4*)(X + (size_t)gr * 128 + c4 * 4);
        int sw = (r & 7) << 2;
        *(float4*)(sX + r * 128 + ((c4 * 4) ^ sw)) = v;
    }
    __syncthreads();

    const int tx = t & 7;
    const int ty = t >> 3;
    float acc[4][8] = {};

    for (int k = 0; k < 128; k += 4) {
        float xk[4][4];
        #pragma unroll
        for (int r = 0; r < 4; ++r) {
            int row = ty + r * 16;
            int sw = (row & 7) << 2;
            float4 v = *(const float4*)(sX + row * 128 + (k ^ sw));
            xk[r][0] = v.x; xk[r][1] = v.y; xk[r][2] = v.z; xk[r][3] = v.w;
        }
        #pragma unroll
        for (int kk = 0; kk < 4; ++kk) {
            const float* wr = sW + (k + kk) * 64 + tx * 8;
            float4 wa = *(const float4*)(wr);
            float4 wb = *(const float4*)(wr + 4);
            float wv[8] = {wa.x, wa.y, wa.z, wa.w, wb.x, wb.y, wb.z, wb.w};
            #pragma unroll
            for (int r = 0; r < 4; ++r) {
                float xs = xk[r][kk];
                #pragma unroll
                for (int c = 0; c < 8; ++c) acc[r][c] += xs * wv[c];
            }
        }
    }

    #pragma unroll
    for (int r = 0; r < 4; ++r) {
        int gr = row0 + ty + r * 16;
        if (gr < n) {
            float* o = H + (size_t)gr * 128 + col0 + tx * 8;
            *(float4*)(o)     = make_float4(acc[r][0], acc[r][1], acc[r][2], acc[r][3]);
            *(float4*)(o + 4) = make_float4(acc[r][4], acc[r][5], acc[r][6], acc[r][7]);
        }
    }
}

// ---------------------------------------------------------------------------
// CSR gather + bias + activation. One 64-lane wave per node, 2 features
// (float2) per lane, 4 edges in flight. ACT: 0 = relu, 1 = sigmoid.
// ---------------------------------------------------------------------------
template <int ACT>
__global__ __launch_bounds__(128) void k_gather(const float2* __restrict__ H2,
                                                const float2* __restrict__ csr,
                                                const int* __restrict__ endp,
                                                const float* __restrict__ dinv,
                                                const float* __restrict__ bias,
                                                float2* __restrict__ out2, int N) {
    int node = blockIdx.x * 2 + (threadIdx.x >> 6);
    if (node >= N) return;
    const int lane = threadIdx.x & 63;
    const int start = (node == 0) ? 0 : endp[node - 1];
    const int end = endp[node];

    // self-loop: ew=1, norm = dinv[node]^2
    float di = dinv[node];
    float2 hv = H2[(size_t)node * 64 + lane];
    float2 acc = make_float2(hv.x * di * di, hv.y * di * di);

    int k = start;
    for (; k + 3 < end; k += 4) {  // 4 independent row loads in flight
        float2 c0 = csr[k], c1 = csr[k + 1], c2 = csr[k + 2], c3 = csr[k + 3];
        int s0 = __float_as_int(c0.x), s1 = __float_as_int(c1.x);
        int s2 = __float_as_int(c2.x), s3 = __float_as_int(c3.x);
        float2 h0 = H2[(size_t)s0 * 64 + lane];
        float2 h1 = H2[(size_t)s1 * 64 + lane];
        float2 h2 = H2[(size_t)s2 * 64 + lane];
        float2 h3 = H2[(size_t)s3 * 64 + lane];
        acc.x += h0.x * c0.y + h1.x * c1.y + h2.x * c2.y + h3.x * c3.y;
        acc.y += h0.y * c0.y + h1.y * c1.y + h2.y * c2.y + h3.y * c3.y;
    }
    for (; k < end; ++k) {
        float2 c0 = csr[k];
        int s0 = __float_as_int(c0.x);
        float2 h0 = H2[(size_t)s0 * 64 + lane];
        acc.x += h0.x * c0.y;
        acc.y += h0.y * c0.y;
    }

    int j = lane * 2;
    acc.x += bias[j];
    acc.y += bias[j + 1];
    if (ACT == 0) {
        acc.x = fmaxf(acc.x, 0.f);
        acc.y = fmaxf(acc.y, 0.f);
    } else {
        acc.x = 1.f / (1.f + expf(-acc.x));
        acc.y = 1.f / (1.f + expf(-acc.y));
    }
    out2[(size_t)node * 64 + lane] = acc;
}

extern "C" void kernel_launch(void* const* d_in, const int* in_sizes, int n_in,
                              void* d_out, int out_size, void* d_ws, size_t ws_size,
                              hipStream_t stream) {
    const float* x  = (const float*)d_in[0];
    const int*   ei = (const int*)d_in[1];
    const float* ew = (const float*)d_in[2];
    const float* W1 = (const float*)d_in[3];
    const float* b1 = (const float*)d_in[4];
    const float* W2 = (const float*)d_in[5];
    const float* b2 = (const float*)d_in[6];

    const int N = in_sizes[0] / 128;
    const int E = in_sizes[2];
    const int* src = ei;
    const int* dst = ei + E;
    float* out = (float*)d_out;

    // Workspace layout (256B-aligned slabs):
    //   dinv [N] | cnt [N+1] | rowptr [N+1] | chunksums [1024] | csr [E f2] | h [N*128]
    auto align = [](size_t v) { return (v + 255) & ~(size_t)255; };
    char* p = (char*)d_ws;
    float*  dinv   = (float*)p;   p += align((size_t)N * 4);
    int*    cnt    = (int*)p;     p += align((size_t)(N + 1) * 4);
    int*    rowptr = (int*)p;     p += align((size_t)(N + 1) * 4);
    int*    csums  = (int*)p;     p += align((size_t)1024 * 4);
    float2* csr    = (float2*)p;  p += align((size_t)E * 8);
    float*  h      = (float*)p;

    const int nbN = (N + 255) / 256;
    const int nbE = (E + 255) / 256;
    const int nScan = N + 1;
    const int gScan = (nScan + 1023) / 1024;  // 1024 elems per scan block
    dim3 ggrid((N + 63) / 64, 2);

    // --- CSR + normalization build (shared by both layers) ---
    hipMemsetAsync(cnt, 0, (size_t)(N + 1) * sizeof(int), stream);
    k_deg_init<<<nbN, 256, 0, stream>>>(dinv, N);
    k_hist<<<nbE, 256, 0, stream>>>(dst, ew, dinv, cnt, E);
    k_dinv<<<nbN, 256, 0, stream>>>(dinv, N);
    k_scan1<<<gScan, 256, 0, stream>>>(cnt, rowptr, csums, nScan);
    k_scan2<<<1, 1024, 0, stream>>>(csums, gScan);
    k_scan3<<<gScan, 256, 0, stream>>>(rowptr, csums, nScan);
    k_fill<<<nbE, 256, 0, stream>>>(src, dst, ew, dinv, rowptr, csr, E);

    // --- Layer 1: h = x@W1 ; out = relu(gather(h) + b1) ---
    k_gemm<<<ggrid, 128, 0, stream>>>(x, W1, h, N);
    k_gather<0><<<(N + 1) / 2, 128, 0, stream>>>((const float2*)h, csr, rowptr,
                                                 dinv, b1, (float2*)out, N);

    // --- Layer 2: h = out@W2 ; out = sigmoid(gather(h) + b2) ---
    k_gemm<<<ggrid, 128, 0, stream>>>(out, W2, h, N);
    k_gather<1><<<(N + 1) / 2, 128, 0, stream>>>((const float2*)h, csr, rowptr,
                                                 dinv, b2, (float2*)out, N);
}

// Round 4
// 355.885 us; speedup vs baseline: 2.3230x; 1.1273x over previous
//
#include <hip/hip_runtime.h>
#include <math.h>

// ---------------------------------------------------------------------------
// GCN 2-layer forward on MI355X (fp32).
// Round 4: GEMM k-chunked LDS staging (64 KB -> 16 KB/block) to lift
// occupancy 9% -> ~50%; gather unroll x8; minor launch trims.
// ---------------------------------------------------------------------------

__global__ __launch_bounds__(256) void k_deg_init(float* __restrict__ deg,
                                                  int* __restrict__ cnt, int n) {
    int i = blockIdx.x * 256 + threadIdx.x;
    if (i < n) { deg[i] = 1.0f; cnt[i] = 0; }
    if (i == 0) cnt[n] = 0;
}

// deg[dst] += ew  and  cnt[dst] += 1  in one pass over edges
__global__ __launch_bounds__(256) void k_hist(const int* __restrict__ dst,
                                              const float* __restrict__ ew,
                                              float* __restrict__ deg,
                                              int* __restrict__ cnt, int e) {
    int i = blockIdx.x * 256 + threadIdx.x;
    if (i < e) {
        int d = dst[i];
        atomicAdd(&deg[d], ew[i]);
        atomicAdd(&cnt[d], 1);
    }
}

__global__ __launch_bounds__(256) void k_dinv(float* __restrict__ deg, int n) {
    int i = blockIdx.x * 256 + threadIdx.x;
    if (i < n) deg[i] = rsqrtf(deg[i]);  // deg >= 1 always (self-loop)
}

// ---------------------------------------------------------------------------
// Hierarchical exclusive scan: out[i] = sum(in[0..i)).
// ---------------------------------------------------------------------------
__global__ __launch_bounds__(256) void k_scan1(const int* __restrict__ in,
                                               int* __restrict__ out,
                                               int* __restrict__ sums, int n) {
    __shared__ int s[256];
    const int t = threadIdx.x;
    const int base = blockIdx.x * 1024 + t * 4;
    int v0 = 0, v1 = 0, v2 = 0, v3 = 0;
    if (base + 0 < n) v0 = in[base + 0];
    if (base + 1 < n) v1 = in[base + 1];
    if (base + 2 < n) v2 = in[base + 2];
    if (base + 3 < n) v3 = in[base + 3];
    s[t] = v0 + v1 + v2 + v3;
    __syncthreads();
    #pragma unroll
    for (int off = 1; off < 256; off <<= 1) {
        int x = (t >= off) ? s[t - off] : 0;
        __syncthreads();
        s[t] += x;
        __syncthreads();
    }
    if (t == 255) sums[blockIdx.x] = s[255];
    int e = (t == 0) ? 0 : s[t - 1];
    if (base + 0 < n) out[base + 0] = e;
    if (base + 1 < n) out[base + 1] = e + v0;
    if (base + 2 < n) out[base + 2] = e + v0 + v1;
    if (base + 3 < n) out[base + 3] = e + v0 + v1 + v2;
}

__global__ __launch_bounds__(256) void k_scan2(int* __restrict__ sums, int g) {
    __shared__ int s[256];
    const int t = threadIdx.x;
    s[t] = (t < g) ? sums[t] : 0;
    __syncthreads();
    #pragma unroll
    for (int off = 1; off < 256; off <<= 1) {
        int x = (t >= off) ? s[t - off] : 0;
        __syncthreads();
        s[t] += x;
        __syncthreads();
    }
    if (t < g) sums[t] = (t == 0) ? 0 : s[t - 1];  // exclusive
}

__global__ __launch_bounds__(256) void k_scan3(int* __restrict__ out,
                                               const int* __restrict__ sums, int n) {
    const int base = blockIdx.x * 1024 + threadIdx.x * 4;
    const int add = sums[blockIdx.x];
    #pragma unroll
    for (int u = 0; u < 4; ++u)
        if (base + u < n) out[base + u] += add;
}

// Fill CSR: csr[pos] = (src, dinv[src]*ew*dinv[dst]). Uses rowptr as cursor;
// after this kernel rowptr[d] == end offset of node d (start = rowptr[d-1]).
__global__ __launch_bounds__(256) void k_fill(const int* __restrict__ src,
                                              const int* __restrict__ dst,
                                              const float* __restrict__ ew,
                                              const float* __restrict__ dinv,
                                              int* __restrict__ rowptr,
                                              float2* __restrict__ csr, int e) {
    int i = blockIdx.x * 256 + threadIdx.x;
    if (i < e) {
        int s = src[i], d = dst[i];
        float nrm = dinv[s] * ew[i] * dinv[d];
        int pos = atomicAdd(&rowptr[d], 1);
        csr[pos] = make_float2(__int_as_float(s), nrm);
    }
}

// ---------------------------------------------------------------------------
// GEMM: H[n x 128] = X[n x 128] @ W[128 x 128]  (fp32, vector ALU)
// 128 threads, 64x64 tile, K chunked by 32: LDS = 8+8 KB -> high occupancy.
// Each thread: 4 rows x 8 cols, float4 LDS reads, XOR swizzle on sX rows.
// ---------------------------------------------------------------------------
__global__ __launch_bounds__(128) void k_gemm(const float* __restrict__ X,
                                              const float* __restrict__ W,
                                              float* __restrict__ H, int n) {
    __shared__ float sW[32 * 64];  // [k][col]   8 KB
    __shared__ float sX[64 * 32];  // [row][k^s] 8 KB
    const int t = threadIdx.x;
    const int row0 = blockIdx.x * 64;
    const int col0 = blockIdx.y * 64;
    const int tx = t & 7;
    const int ty = t >> 3;
    float acc[4][8] = {};

    for (int c = 0; c < 4; ++c) {
        // stage W rows [c*32, c*32+32), cols [col0, col0+64): 512 float4
        for (int i = t; i < 512; i += 128) {
            int k = i >> 4, c4 = i & 15;
            *(float4*)(sW + k * 64 + c4 * 4) =
                *(const float4*)(W + (size_t)(c * 32 + k) * 128 + col0 + c4 * 4);
        }
        // stage X rows [row0, row0+64), k [c*32, c*32+32): 512 float4, swizzled
        for (int i = t; i < 512; i += 128) {
            int r = i >> 3, c4 = i & 7;
            int gr = row0 + r;
            float4 v = make_float4(0.f, 0.f, 0.f, 0.f);
            if (gr < n) v = *(const float4*)(X + (size_t)gr * 128 + c * 32 + c4 * 4);
            int sw = (r & 7) << 2;
            *(float4*)(sX + r * 32 + ((c4 * 4) ^ sw)) = v;
        }
        __syncthreads();

        #pragma unroll
        for (int k = 0; k < 32; k += 4) {
            float xk[4][4];
            #pragma unroll
            for (int r = 0; r < 4; ++r) {
                int row = ty + r * 16;
                int sw = (row & 7) << 2;
                float4 v = *(const float4*)(sX + row * 32 + (k ^ sw));
                xk[r][0] = v.x; xk[r][1] = v.y; xk[r][2] = v.z; xk[r][3] = v.w;
            }
            #pragma unroll
            for (int kk = 0; kk < 4; ++kk) {
                const float* wr = sW + (k + kk) * 64 + tx * 8;
                float4 wa = *(const float4*)(wr);
                float4 wb = *(const float4*)(wr + 4);
                float wv[8] = {wa.x, wa.y, wa.z, wa.w, wb.x, wb.y, wb.z, wb.w};
                #pragma unroll
                for (int r = 0; r < 4; ++r) {
                    float xs = xk[r][kk];
                    #pragma unroll
                    for (int cc = 0; cc < 8; ++cc) acc[r][cc] += xs * wv[cc];
                }
            }
        }
        __syncthreads();
    }

    #pragma unroll
    for (int r = 0; r < 4; ++r) {
        int gr = row0 + ty + r * 16;
        if (gr < n) {
            float* o = H + (size_t)gr * 128 + col0 + tx * 8;
            *(float4*)(o)     = make_float4(acc[r][0], acc[r][1], acc[r][2], acc[r][3]);
            *(float4*)(o + 4) = make_float4(acc[r][4], acc[r][5], acc[r][6], acc[r][7]);
        }
    }
}

// ---------------------------------------------------------------------------
// CSR gather + bias + activation. One 64-lane wave per node, 2 features
// (float2) per lane, 8 edges in flight. ACT: 0 = relu, 1 = sigmoid.
// ---------------------------------------------------------------------------
template <int ACT>
__global__ __launch_bounds__(128) void k_gather(const float2* __restrict__ H2,
                                                const float2* __restrict__ csr,
                                                const int* __restrict__ endp,
                                                const float* __restrict__ dinv,
                                                const float* __restrict__ bias,
                                                float2* __restrict__ out2, int N) {
    int node = blockIdx.x * 2 + (threadIdx.x >> 6);
    if (node >= N) return;
    const int lane = threadIdx.x & 63;
    const int start = (node == 0) ? 0 : endp[node - 1];
    const int end = endp[node];

    // self-loop: ew=1, norm = dinv[node]^2
    float di = dinv[node];
    float2 hv = H2[(size_t)node * 64 + lane];
    float2 acc = make_float2(hv.x * di * di, hv.y * di * di);

    int k = start;
    for (; k + 7 < end; k += 8) {  // 8 independent row loads in flight
        float2 c[8], hh[8];
        #pragma unroll
        for (int u = 0; u < 8; ++u) c[u] = csr[k + u];
        #pragma unroll
        for (int u = 0; u < 8; ++u)
            hh[u] = H2[(size_t)__float_as_int(c[u].x) * 64 + lane];
        #pragma unroll
        for (int u = 0; u < 8; ++u) {
            acc.x += hh[u].x * c[u].y;
            acc.y += hh[u].y * c[u].y;
        }
    }
    for (; k < end; ++k) {
        float2 c0 = csr[k];
        float2 h0 = H2[(size_t)__float_as_int(c0.x) * 64 + lane];
        acc.x += h0.x * c0.y;
        acc.y += h0.y * c0.y;
    }

    int j = lane * 2;
    acc.x += bias[j];
    acc.y += bias[j + 1];
    if (ACT == 0) {
        acc.x = fmaxf(acc.x, 0.f);
        acc.y = fmaxf(acc.y, 0.f);
    } else {
        acc.x = 1.f / (1.f + expf(-acc.x));
        acc.y = 1.f / (1.f + expf(-acc.y));
    }
    out2[(size_t)node * 64 + lane] = acc;
}

extern "C" void kernel_launch(void* const* d_in, const int* in_sizes, int n_in,
                              void* d_out, int out_size, void* d_ws, size_t ws_size,
                              hipStream_t stream) {
    const float* x  = (const float*)d_in[0];
    const int*   ei = (const int*)d_in[1];
    const float* ew = (const float*)d_in[2];
    const float* W1 = (const float*)d_in[3];
    const float* b1 = (const float*)d_in[4];
    const float* W2 = (const float*)d_in[5];
    const float* b2 = (const float*)d_in[6];

    const int N = in_sizes[0] / 128;
    const int E = in_sizes[2];
    const int* src = ei;
    const int* dst = ei + E;
    float* out = (float*)d_out;

    // Workspace layout (256B-aligned slabs):
    //   dinv [N] | cnt [N+1] | rowptr [N+1] | chunksums [1024] | csr [E f2] | h [N*128]
    auto align = [](size_t v) { return (v + 255) & ~(size_t)255; };
    char* p = (char*)d_ws;
    float*  dinv   = (float*)p;   p += align((size_t)N * 4);
    int*    cnt    = (int*)p;     p += align((size_t)(N + 1) * 4);
    int*    rowptr = (int*)p;     p += align((size_t)(N + 1) * 4);
    int*    csums  = (int*)p;     p += align((size_t)1024 * 4);
    float2* csr    = (float2*)p;  p += align((size_t)E * 8);
    float*  h      = (float*)p;

    const int nbN = (N + 255) / 256;
    const int nbE = (E + 255) / 256;
    const int nScan = N + 1;
    const int gScan = (nScan + 1023) / 1024;  // 1024 elems per scan block (<=256 chunks)
    dim3 ggrid((N + 63) / 64, 2);

    // --- CSR + normalization build (shared by both layers) ---
    k_deg_init<<<nbN, 256, 0, stream>>>(dinv, cnt, N);
    k_hist<<<nbE, 256, 0, stream>>>(dst, ew, dinv, cnt, E);
    k_dinv<<<nbN, 256, 0, stream>>>(dinv, N);
    k_scan1<<<gScan, 256, 0, stream>>>(cnt, rowptr, csums, nScan);
    k_scan2<<<1, 256, 0, stream>>>(csums, gScan);
    k_scan3<<<gScan, 256, 0, stream>>>(rowptr, csums, nScan);
    k_fill<<<nbE, 256, 0, stream>>>(src, dst, ew, dinv, rowptr, csr, E);

    // --- Layer 1: h = x@W1 ; out = relu(gather(h) + b1) ---
    k_gemm<<<ggrid, 128, 0, stream>>>(x, W1, h, N);
    k_gather<0><<<(N + 1) / 2, 128, 0, stream>>>((const float2*)h, csr, rowptr,
                                                 dinv, b1, (float2*)out, N);

    // --- Layer 2: h = out@W2 ; out = sigmoid(gather(h) + b2) ---
    k_gemm<<<ggrid, 128, 0, stream>>>(out, W2, h, N);
    k_gather<1><<<(N + 1) / 2, 128, 0, stream>>>((const float2*)h, csr, rowptr,
                                                 dinv, b2, (float2*)out, N);
}

// Round 5
// 332.529 us; speedup vs baseline: 2.4862x; 1.0702x over previous
//
#include <hip/hip_runtime.h>
#include <math.h>

// ---------------------------------------------------------------------------
// GCN 2-layer forward on MI355X (fp32).
// Round 5: k_hist's 1.2M atomics (57 us, RMW-serialization-bound) -> 600k
// packed u64 atomics: packed[d] = (cnt<<44) | Q.32 fixed-point sum(ew).
// Max deg << 2^12 so no carry into cnt; 2^-24 rel. quantization is invisible.
// ---------------------------------------------------------------------------

// One u64 atomic per edge: +1 in the count field, +ew in the Q.32 sum field.
__global__ __launch_bounds__(256) void k_hist(const int* __restrict__ dst,
                                              const float* __restrict__ ew,
                                              unsigned long long* __restrict__ packed,
                                              int e) {
    int i = blockIdx.x * 256 + threadIdx.x;
    if (i < e) {
        int d = dst[i];
        unsigned long long add =
            (1ULL << 44) + (unsigned long long)(ew[i] * 4294967296.0f);
        atomicAdd(&packed[d], add);
    }
}

// Decode: dinv[i] = rsqrt(1 + sum*2^-32), cnt[i] = packed >> 44.
__global__ __launch_bounds__(256) void k_decode(const unsigned long long* __restrict__ packed,
                                                float* __restrict__ dinv,
                                                int* __restrict__ cnt, int n) {
    int i = blockIdx.x * 256 + threadIdx.x;
    if (i < n) {
        unsigned long long pv = packed[i];
        float deg = 1.0f + (float)(pv & ((1ULL << 44) - 1)) * (1.0f / 4294967296.0f);
        dinv[i] = rsqrtf(deg);
        cnt[i] = (int)(pv >> 44);
    }
    if (i == 0) cnt[n] = 0;
}

// ---------------------------------------------------------------------------
// Hierarchical exclusive scan: out[i] = sum(in[0..i)).
// ---------------------------------------------------------------------------
__global__ __launch_bounds__(256) void k_scan1(const int* __restrict__ in,
                                               int* __restrict__ out,
                                               int* __restrict__ sums, int n) {
    __shared__ int s[256];
    const int t = threadIdx.x;
    const int base = blockIdx.x * 1024 + t * 4;
    int v0 = 0, v1 = 0, v2 = 0, v3 = 0;
    if (base + 0 < n) v0 = in[base + 0];
    if (base + 1 < n) v1 = in[base + 1];
    if (base + 2 < n) v2 = in[base + 2];
    if (base + 3 < n) v3 = in[base + 3];
    s[t] = v0 + v1 + v2 + v3;
    __syncthreads();
    #pragma unroll
    for (int off = 1; off < 256; off <<= 1) {
        int x = (t >= off) ? s[t - off] : 0;
        __syncthreads();
        s[t] += x;
        __syncthreads();
    }
    if (t == 255) sums[blockIdx.x] = s[255];
    int e = (t == 0) ? 0 : s[t - 1];
    if (base + 0 < n) out[base + 0] = e;
    if (base + 1 < n) out[base + 1] = e + v0;
    if (base + 2 < n) out[base + 2] = e + v0 + v1;
    if (base + 3 < n) out[base + 3] = e + v0 + v1 + v2;
}

__global__ __launch_bounds__(256) void k_scan2(int* __restrict__ sums, int g) {
    __shared__ int s[256];
    const int t = threadIdx.x;
    s[t] = (t < g) ? sums[t] : 0;
    __syncthreads();
    #pragma unroll
    for (int off = 1; off < 256; off <<= 1) {
        int x = (t >= off) ? s[t - off] : 0;
        __syncthreads();
        s[t] += x;
        __syncthreads();
    }
    if (t < g) sums[t] = (t == 0) ? 0 : s[t - 1];  // exclusive
}

__global__ __launch_bounds__(256) void k_scan3(int* __restrict__ out,
                                               const int* __restrict__ sums, int n) {
    const int base = blockIdx.x * 1024 + threadIdx.x * 4;
    const int add = sums[blockIdx.x];
    #pragma unroll
    for (int u = 0; u < 4; ++u)
        if (base + u < n) out[base + u] += add;
}

// Fill CSR: csr[pos] = (src, dinv[src]*ew*dinv[dst]). Uses rowptr as cursor;
// after this kernel rowptr[d] == end offset of node d (start = rowptr[d-1]).
__global__ __launch_bounds__(256) void k_fill(const int* __restrict__ src,
                                              const int* __restrict__ dst,
                                              const float* __restrict__ ew,
                                              const float* __restrict__ dinv,
                                              int* __restrict__ rowptr,
                                              float2* __restrict__ csr, int e) {
    int i = blockIdx.x * 256 + threadIdx.x;
    if (i < e) {
        int s = src[i], d = dst[i];
        float nrm = dinv[s] * ew[i] * dinv[d];
        int pos = atomicAdd(&rowptr[d], 1);
        csr[pos] = make_float2(__int_as_float(s), nrm);
    }
}

// ---------------------------------------------------------------------------
// GEMM: H[n x 128] = X[n x 128] @ W[128 x 128]  (fp32, vector ALU)
// 128 threads, 64x64 tile, K chunked by 32: LDS = 8+8 KB -> high occupancy.
// ---------------------------------------------------------------------------
__global__ __launch_bounds__(128) void k_gemm(const float* __restrict__ X,
                                              const float* __restrict__ W,
                                              float* __restrict__ H, int n) {
    __shared__ float sW[32 * 64];  // [k][col]   8 KB
    __shared__ float sX[64 * 32];  // [row][k^s] 8 KB
    const int t = threadIdx.x;
    const int row0 = blockIdx.x * 64;
    const int col0 = blockIdx.y * 64;
    const int tx = t & 7;
    const int ty = t >> 3;
    float acc[4][8] = {};

    for (int c = 0; c < 4; ++c) {
        for (int i = t; i < 512; i += 128) {
            int k = i >> 4, c4 = i & 15;
            *(float4*)(sW + k * 64 + c4 * 4) =
                *(const float4*)(W + (size_t)(c * 32 + k) * 128 + col0 + c4 * 4);
        }
        for (int i = t; i < 512; i += 128) {
            int r = i >> 3, c4 = i & 7;
            int gr = row0 + r;
            float4 v = make_float4(0.f, 0.f, 0.f, 0.f);
            if (gr < n) v = *(const float4*)(X + (size_t)gr * 128 + c * 32 + c4 * 4);
            int sw = (r & 7) << 2;
            *(float4*)(sX + r * 32 + ((c4 * 4) ^ sw)) = v;
        }
        __syncthreads();

        #pragma unroll
        for (int k = 0; k < 32; k += 4) {
            float xk[4][4];
            #pragma unroll
            for (int r = 0; r < 4; ++r) {
                int row = ty + r * 16;
                int sw = (row & 7) << 2;
                float4 v = *(const float4*)(sX + row * 32 + (k ^ sw));
                xk[r][0] = v.x; xk[r][1] = v.y; xk[r][2] = v.z; xk[r][3] = v.w;
            }
            #pragma unroll
            for (int kk = 0; kk < 4; ++kk) {
                const float* wr = sW + (k + kk) * 64 + tx * 8;
                float4 wa = *(const float4*)(wr);
                float4 wb = *(const float4*)(wr + 4);
                float wv[8] = {wa.x, wa.y, wa.z, wa.w, wb.x, wb.y, wb.z, wb.w};
                #pragma unroll
                for (int r = 0; r < 4; ++r) {
                    float xs = xk[r][kk];
                    #pragma unroll
                    for (int cc = 0; cc < 8; ++cc) acc[r][cc] += xs * wv[cc];
                }
            }
        }
        __syncthreads();
    }

    #pragma unroll
    for (int r = 0; r < 4; ++r) {
        int gr = row0 + ty + r * 16;
        if (gr < n) {
            float* o = H + (size_t)gr * 128 + col0 + tx * 8;
            *(float4*)(o)     = make_float4(acc[r][0], acc[r][1], acc[r][2], acc[r][3]);
            *(float4*)(o + 4) = make_float4(acc[r][4], acc[r][5], acc[r][6], acc[r][7]);
        }
    }
}

// ---------------------------------------------------------------------------
// CSR gather + bias + activation. One 64-lane wave per node, 2 features
// (float2) per lane, 8 edges in flight. ACT: 0 = relu, 1 = sigmoid.
// ---------------------------------------------------------------------------
template <int ACT>
__global__ __launch_bounds__(128) void k_gather(const float2* __restrict__ H2,
                                                const float2* __restrict__ csr,
                                                const int* __restrict__ endp,
                                                const float* __restrict__ dinv,
                                                const float* __restrict__ bias,
                                                float2* __restrict__ out2, int N) {
    int node = blockIdx.x * 2 + (threadIdx.x >> 6);
    if (node >= N) return;
    const int lane = threadIdx.x & 63;
    const int start = (node == 0) ? 0 : endp[node - 1];
    const int end = endp[node];

    // self-loop: ew=1, norm = dinv[node]^2
    float di = dinv[node];
    float2 hv = H2[(size_t)node * 64 + lane];
    float2 acc = make_float2(hv.x * di * di, hv.y * di * di);

    int k = start;
    for (; k + 7 < end; k += 8) {  // 8 independent row loads in flight
        float2 c[8], hh[8];
        #pragma unroll
        for (int u = 0; u < 8; ++u) c[u] = csr[k + u];
        #pragma unroll
        for (int u = 0; u < 8; ++u)
            hh[u] = H2[(size_t)__float_as_int(c[u].x) * 64 + lane];
        #pragma unroll
        for (int u = 0; u < 8; ++u) {
            acc.x += hh[u].x * c[u].y;
            acc.y += hh[u].y * c[u].y;
        }
    }
    for (; k < end; ++k) {
        float2 c0 = csr[k];
        float2 h0 = H2[(size_t)__float_as_int(c0.x) * 64 + lane];
        acc.x += h0.x * c0.y;
        acc.y += h0.y * c0.y;
    }

    int j = lane * 2;
    acc.x += bias[j];
    acc.y += bias[j + 1];
    if (ACT == 0) {
        acc.x = fmaxf(acc.x, 0.f);
        acc.y = fmaxf(acc.y, 0.f);
    } else {
        acc.x = 1.f / (1.f + expf(-acc.x));
        acc.y = 1.f / (1.f + expf(-acc.y));
    }
    out2[(size_t)node * 64 + lane] = acc;
}

extern "C" void kernel_launch(void* const* d_in, const int* in_sizes, int n_in,
                              void* d_out, int out_size, void* d_ws, size_t ws_size,
                              hipStream_t stream) {
    const float* x  = (const float*)d_in[0];
    const int*   ei = (const int*)d_in[1];
    const float* ew = (const float*)d_in[2];
    const float* W1 = (const float*)d_in[3];
    const float* b1 = (const float*)d_in[4];
    const float* W2 = (const float*)d_in[5];
    const float* b2 = (const float*)d_in[6];

    const int N = in_sizes[0] / 128;
    const int E = in_sizes[2];
    const int* src = ei;
    const int* dst = ei + E;
    float* out = (float*)d_out;

    // Workspace layout (256B-aligned slabs):
    //   packed [N u64] | dinv [N] | cnt [N+1] | rowptr [N+1] | csums [1024]
    //   | csr [E f2] | h [N*128]
    auto align = [](size_t v) { return (v + 255) & ~(size_t)255; };
    char* p = (char*)d_ws;
    unsigned long long* packed = (unsigned long long*)p; p += align((size_t)N * 8);
    float*  dinv   = (float*)p;   p += align((size_t)N * 4);
    int*    cnt    = (int*)p;     p += align((size_t)(N + 1) * 4);
    int*    rowptr = (int*)p;     p += align((size_t)(N + 1) * 4);
    int*    csums  = (int*)p;     p += align((size_t)1024 * 4);
    float2* csr    = (float2*)p;  p += align((size_t)E * 8);
    float*  h      = (float*)p;

    const int nbN = (N + 255) / 256;
    const int nbE = (E + 255) / 256;
    const int nScan = N + 1;
    const int gScan = (nScan + 1023) / 1024;  // 1024 elems per scan block (<=256 chunks)
    dim3 ggrid((N + 63) / 64, 2);

    // --- CSR + normalization build (shared by both layers) ---
    hipMemsetAsync(packed, 0, (size_t)N * 8, stream);
    k_hist<<<nbE, 256, 0, stream>>>(dst, ew, packed, E);
    k_decode<<<nbN, 256, 0, stream>>>(packed, dinv, cnt, N);
    k_scan1<<<gScan, 256, 0, stream>>>(cnt, rowptr, csums, nScan);
    k_scan2<<<1, 256, 0, stream>>>(csums, gScan);
    k_scan3<<<gScan, 256, 0, stream>>>(rowptr, csums, nScan);
    k_fill<<<nbE, 256, 0, stream>>>(src, dst, ew, dinv, rowptr, csr, E);

    // --- Layer 1: h = x@W1 ; out = relu(gather(h) + b1) ---
    k_gemm<<<ggrid, 128, 0, stream>>>(x, W1, h, N);
    k_gather<0><<<(N + 1) / 2, 128, 0, stream>>>((const float2*)h, csr, rowptr,
                                                 dinv, b1, (float2*)out, N);

    // --- Layer 2: h = out@W2 ; out = sigmoid(gather(h) + b2) ---
    k_gemm<<<ggrid, 128, 0, stream>>>(out, W2, h, N);
    k_gather<1><<<(N + 1) / 2, 128, 0, stream>>>((const float2*)h, csr, rowptr,
                                                 dinv, b2, (float2*)out, N);
}

// Round 6
// 306.975 us; speedup vs baseline: 2.6931x; 1.0832x over previous
//
#include <hip/hip_runtime.h>
#include <math.h>

// ---------------------------------------------------------------------------
// GCN 2-layer forward on MI355X.
// Round 6: h (internal GEMM output) stored as bf16 -> halves the random
// gather fetch traffic (145.6 MB -> ~75 MB per layer), which R5 counters
// showed is the bottleneck (43% HBM, VALU 24%). Accumulation stays fp32;
// bf16->fp32 decode is an exact shift.
// ---------------------------------------------------------------------------

typedef unsigned int uint32;
typedef unsigned short ushort16;

// One u64 atomic per edge: +1 in the count field, +ew in the Q.32 sum field.
__global__ __launch_bounds__(256) void k_hist(const int* __restrict__ dst,
                                              const float* __restrict__ ew,
                                              unsigned long long* __restrict__ packed,
                                              int e) {
    int i = blockIdx.x * 256 + threadIdx.x;
    if (i < e) {
        int d = dst[i];
        unsigned long long add =
            (1ULL << 44) + (unsigned long long)(ew[i] * 4294967296.0f);
        atomicAdd(&packed[d], add);
    }
}

// Decode: dinv[i] = rsqrt(1 + sum*2^-32), cnt[i] = packed >> 44.
__global__ __launch_bounds__(256) void k_decode(const unsigned long long* __restrict__ packed,
                                                float* __restrict__ dinv,
                                                int* __restrict__ cnt, int n) {
    int i = blockIdx.x * 256 + threadIdx.x;
    if (i < n) {
        unsigned long long pv = packed[i];
        float deg = 1.0f + (float)(pv & ((1ULL << 44) - 1)) * (1.0f / 4294967296.0f);
        dinv[i] = rsqrtf(deg);
        cnt[i] = (int)(pv >> 44);
    }
    if (i == 0) cnt[n] = 0;
}

// ---------------------------------------------------------------------------
// Hierarchical exclusive scan: out[i] = sum(in[0..i)).
// ---------------------------------------------------------------------------
__global__ __launch_bounds__(256) void k_scan1(const int* __restrict__ in,
                                               int* __restrict__ out,
                                               int* __restrict__ sums, int n) {
    __shared__ int s[256];
    const int t = threadIdx.x;
    const int base = blockIdx.x * 1024 + t * 4;
    int v0 = 0, v1 = 0, v2 = 0, v3 = 0;
    if (base + 0 < n) v0 = in[base + 0];
    if (base + 1 < n) v1 = in[base + 1];
    if (base + 2 < n) v2 = in[base + 2];
    if (base + 3 < n) v3 = in[base + 3];
    s[t] = v0 + v1 + v2 + v3;
    __syncthreads();
    #pragma unroll
    for (int off = 1; off < 256; off <<= 1) {
        int x = (t >= off) ? s[t - off] : 0;
        __syncthreads();
        s[t] += x;
        __syncthreads();
    }
    if (t == 255) sums[blockIdx.x] = s[255];
    int e = (t == 0) ? 0 : s[t - 1];
    if (base + 0 < n) out[base + 0] = e;
    if (base + 1 < n) out[base + 1] = e + v0;
    if (base + 2 < n) out[base + 2] = e + v0 + v1;
    if (base + 3 < n) out[base + 3] = e + v0 + v1 + v2;
}

__global__ __launch_bounds__(256) void k_scan2(int* __restrict__ sums, int g) {
    __shared__ int s[256];
    const int t = threadIdx.x;
    s[t] = (t < g) ? sums[t] : 0;
    __syncthreads();
    #pragma unroll
    for (int off = 1; off < 256; off <<= 1) {
        int x = (t >= off) ? s[t - off] : 0;
        __syncthreads();
        s[t] += x;
        __syncthreads();
    }
    if (t < g) sums[t] = (t == 0) ? 0 : s[t - 1];  // exclusive
}

__global__ __launch_bounds__(256) void k_scan3(int* __restrict__ out,
                                               const int* __restrict__ sums, int n) {
    const int base = blockIdx.x * 1024 + threadIdx.x * 4;
    const int add = sums[blockIdx.x];
    #pragma unroll
    for (int u = 0; u < 4; ++u)
        if (base + u < n) out[base + u] += add;
}

// Fill CSR: csr[pos] = (src, dinv[src]*ew*dinv[dst]). Uses rowptr as cursor;
// after this kernel rowptr[d] == end offset of node d (start = rowptr[d-1]).
__global__ __launch_bounds__(256) void k_fill(const int* __restrict__ src,
                                              const int* __restrict__ dst,
                                              const float* __restrict__ ew,
                                              const float* __restrict__ dinv,
                                              int* __restrict__ rowptr,
                                              float2* __restrict__ csr, int e) {
    int i = blockIdx.x * 256 + threadIdx.x;
    if (i < e) {
        int s = src[i], d = dst[i];
        float nrm = dinv[s] * ew[i] * dinv[d];
        int pos = atomicAdd(&rowptr[d], 1);
        csr[pos] = make_float2(__int_as_float(s), nrm);
    }
}

// ---------------------------------------------------------------------------
// GEMM: H[n x 128] = X[n x 128] @ W[128 x 128]  (fp32 compute, bf16 output)
// 128 threads, 64x64 tile, K chunked by 32: LDS = 8+8 KB -> high occupancy.
// ---------------------------------------------------------------------------
__global__ __launch_bounds__(128) void k_gemm(const float* __restrict__ X,
                                              const float* __restrict__ W,
                                              ushort16* __restrict__ H, int n) {
    __shared__ float sW[32 * 64];  // [k][col]   8 KB
    __shared__ float sX[64 * 32];  // [row][k^s] 8 KB
    const int t = threadIdx.x;
    const int row0 = blockIdx.x * 64;
    const int col0 = blockIdx.y * 64;
    const int tx = t & 7;
    const int ty = t >> 3;
    float acc[4][8] = {};

    for (int c = 0; c < 4; ++c) {
        for (int i = t; i < 512; i += 128) {
            int k = i >> 4, c4 = i & 15;
            *(float4*)(sW + k * 64 + c4 * 4) =
                *(const float4*)(W + (size_t)(c * 32 + k) * 128 + col0 + c4 * 4);
        }
        for (int i = t; i < 512; i += 128) {
            int r = i >> 3, c4 = i & 7;
            int gr = row0 + r;
            float4 v = make_float4(0.f, 0.f, 0.f, 0.f);
            if (gr < n) v = *(const float4*)(X + (size_t)gr * 128 + c * 32 + c4 * 4);
            int sw = (r & 7) << 2;
            *(float4*)(sX + r * 32 + ((c4 * 4) ^ sw)) = v;
        }
        __syncthreads();

        #pragma unroll
        for (int k = 0; k < 32; k += 4) {
            float xk[4][4];
            #pragma unroll
            for (int r = 0; r < 4; ++r) {
                int row = ty + r * 16;
                int sw = (row & 7) << 2;
                float4 v = *(const float4*)(sX + row * 32 + (k ^ sw));
                xk[r][0] = v.x; xk[r][1] = v.y; xk[r][2] = v.z; xk[r][3] = v.w;
            }
            #pragma unroll
            for (int kk = 0; kk < 4; ++kk) {
                const float* wr = sW + (k + kk) * 64 + tx * 8;
                float4 wa = *(const float4*)(wr);
                float4 wb = *(const float4*)(wr + 4);
                float wv[8] = {wa.x, wa.y, wa.z, wa.w, wb.x, wb.y, wb.z, wb.w};
                #pragma unroll
                for (int r = 0; r < 4; ++r) {
                    float xs = xk[r][kk];
                    #pragma unroll
                    for (int cc = 0; cc < 8; ++cc) acc[r][cc] += xs * wv[cc];
                }
            }
        }
        __syncthreads();
    }

    #pragma unroll
    for (int r = 0; r < 4; ++r) {
        int gr = row0 + ty + r * 16;
        if (gr < n) {
            uint32 pk[4];
            #pragma unroll
            for (int c2 = 0; c2 < 4; ++c2) {
                uint32 b0 = __float_as_uint(acc[r][c2 * 2]);
                uint32 b1 = __float_as_uint(acc[r][c2 * 2 + 1]);
                b0 = (b0 + 0x7FFFu + ((b0 >> 16) & 1u)) >> 16;  // RNE to bf16
                b1 = (b1 + 0x7FFFu + ((b1 >> 16) & 1u)) >> 16;
                pk[c2] = b0 | (b1 << 16);
            }
            uint4 v; v.x = pk[0]; v.y = pk[1]; v.z = pk[2]; v.w = pk[3];
            *(uint4*)(H + (size_t)gr * 128 + col0 + tx * 8) = v;  // 8 bf16 = 16 B
        }
    }
}

// ---------------------------------------------------------------------------
// CSR gather + bias + activation. One 64-lane wave per node, 2 bf16 features
// (one uint) per lane, 8 edges in flight, fp32 accumulation.
// ACT: 0 = relu, 1 = sigmoid.
// ---------------------------------------------------------------------------
__device__ __forceinline__ float2 bf2_decode(uint32 u) {
    return make_float2(__uint_as_float(u << 16),
                       __uint_as_float(u & 0xFFFF0000u));
}

template <int ACT>
__global__ __launch_bounds__(128) void k_gather(const uint32* __restrict__ Hb,
                                                const float2* __restrict__ csr,
                                                const int* __restrict__ endp,
                                                const float* __restrict__ dinv,
                                                const float* __restrict__ bias,
                                                float2* __restrict__ out2, int N) {
    int node = blockIdx.x * 2 + (threadIdx.x >> 6);
    if (node >= N) return;
    const int lane = threadIdx.x & 63;
    const int start = (node == 0) ? 0 : endp[node - 1];
    const int end = endp[node];

    // self-loop: ew=1, norm = dinv[node]^2
    float di = dinv[node];
    float2 hv = bf2_decode(Hb[(size_t)node * 64 + lane]);
    float2 acc = make_float2(hv.x * di * di, hv.y * di * di);

    int k = start;
    for (; k + 7 < end; k += 8) {  // 8 independent row loads in flight
        float2 c[8];
        uint32 hu[8];
        #pragma unroll
        for (int u = 0; u < 8; ++u) c[u] = csr[k + u];
        #pragma unroll
        for (int u = 0; u < 8; ++u)
            hu[u] = Hb[(size_t)__float_as_int(c[u].x) * 64 + lane];
        #pragma unroll
        for (int u = 0; u < 8; ++u) {
            float2 hh = bf2_decode(hu[u]);
            acc.x += hh.x * c[u].y;
            acc.y += hh.y * c[u].y;
        }
    }
    for (; k < end; ++k) {
        float2 c0 = csr[k];
        float2 h0 = bf2_decode(Hb[(size_t)__float_as_int(c0.x) * 64 + lane]);
        acc.x += h0.x * c0.y;
        acc.y += h0.y * c0.y;
    }

    int j = lane * 2;
    acc.x += bias[j];
    acc.y += bias[j + 1];
    if (ACT == 0) {
        acc.x = fmaxf(acc.x, 0.f);
        acc.y = fmaxf(acc.y, 0.f);
    } else {
        acc.x = 1.f / (1.f + expf(-acc.x));
        acc.y = 1.f / (1.f + expf(-acc.y));
    }
    out2[(size_t)node * 64 + lane] = acc;
}

extern "C" void kernel_launch(void* const* d_in, const int* in_sizes, int n_in,
                              void* d_out, int out_size, void* d_ws, size_t ws_size,
                              hipStream_t stream) {
    const float* x  = (const float*)d_in[0];
    const int*   ei = (const int*)d_in[1];
    const float* ew = (const float*)d_in[2];
    const float* W1 = (const float*)d_in[3];
    const float* b1 = (const float*)d_in[4];
    const float* W2 = (const float*)d_in[5];
    const float* b2 = (const float*)d_in[6];

    const int N = in_sizes[0] / 128;
    const int E = in_sizes[2];
    const int* src = ei;
    const int* dst = ei + E;
    float* out = (float*)d_out;

    // Workspace layout (256B-aligned slabs):
    //   packed [N u64] | dinv [N] | cnt [N+1] | rowptr [N+1] | csums [1024]
    //   | csr [E f2] | h_bf16 [N*128 u16]
    auto align = [](size_t v) { return (v + 255) & ~(size_t)255; };
    char* p = (char*)d_ws;
    unsigned long long* packed = (unsigned long long*)p; p += align((size_t)N * 8);
    float*  dinv   = (float*)p;   p += align((size_t)N * 4);
    int*    cnt    = (int*)p;     p += align((size_t)(N + 1) * 4);
    int*    rowptr = (int*)p;     p += align((size_t)(N + 1) * 4);
    int*    csums  = (int*)p;     p += align((size_t)1024 * 4);
    float2* csr    = (float2*)p;  p += align((size_t)E * 8);
    ushort16* h    = (ushort16*)p;

    const int nbN = (N + 255) / 256;
    const int nbE = (E + 255) / 256;
    const int nScan = N + 1;
    const int gScan = (nScan + 1023) / 1024;  // 1024 elems per scan block (<=256 chunks)
    dim3 ggrid((N + 63) / 64, 2);

    // --- CSR + normalization build (shared by both layers) ---
    hipMemsetAsync(packed, 0, (size_t)N * 8, stream);
    k_hist<<<nbE, 256, 0, stream>>>(dst, ew, packed, E);
    k_decode<<<nbN, 256, 0, stream>>>(packed, dinv, cnt, N);
    k_scan1<<<gScan, 256, 0, stream>>>(cnt, rowptr, csums, nScan);
    k_scan2<<<1, 256, 0, stream>>>(csums, gScan);
    k_scan3<<<gScan, 256, 0, stream>>>(rowptr, csums, nScan);
    k_fill<<<nbE, 256, 0, stream>>>(src, dst, ew, dinv, rowptr, csr, E);

    // --- Layer 1: h = bf16(x@W1) ; out = relu(gather(h) + b1) ---
    k_gemm<<<ggrid, 128, 0, stream>>>(x, W1, h, N);
    k_gather<0><<<(N + 1) / 2, 128, 0, stream>>>((const uint32*)h, csr, rowptr,
                                                 dinv, b1, (float2*)out, N);

    // --- Layer 2: h = bf16(out@W2) ; out = sigmoid(gather(h) + b2) ---
    k_gemm<<<ggrid, 128, 0, stream>>>(out, W2, h, N);
    k_gather<1><<<(N + 1) / 2, 128, 0, stream>>>((const uint32*)h, csr, rowptr,
                                                 dinv, b2, (float2*)out, N);
}

// Round 7
// 264.161 us; speedup vs baseline: 3.1296x; 1.1621x over previous
//
#include <hip/hip_runtime.h>
#include <math.h>

// ---------------------------------------------------------------------------
// GCN 2-layer forward on MI355X.
// Round 7: GEMMs moved to MFMA (v_mfma_f32_16x16x32_bf16). W pre-transposed
// + bf16-converted once; X converted inline; layer-2 input produced as bf16
// directly by gather-1. No LDS: A-frags stream from global in MFMA A-layout
// (A[m=lane&15][k=quad*8+j]); B-frags from 32 KB L1-resident WT. fp32 accum,
// bf16 output (what the gather wants anyway).
// ---------------------------------------------------------------------------

typedef unsigned int uint32;
typedef __attribute__((ext_vector_type(8))) short bf16x8;   // 8 bf16 (4 VGPRs)
typedef __attribute__((ext_vector_type(4))) float f32x4;

__device__ __forceinline__ unsigned short f2bf(float f) {   // RNE fp32->bf16
    uint32 b = __float_as_uint(f);
    return (unsigned short)((b + 0x7FFFu + ((b >> 16) & 1u)) >> 16);
}

// One u64 atomic per edge: +1 in the count field, +ew in the Q.32 sum field.
__global__ __launch_bounds__(256) void k_hist(const int* __restrict__ dst,
                                              const float* __restrict__ ew,
                                              unsigned long long* __restrict__ packed,
                                              int e) {
    int i = blockIdx.x * 256 + threadIdx.x;
    if (i < e) {
        int d = dst[i];
        unsigned long long add =
            (1ULL << 44) + (unsigned long long)(ew[i] * 4294967296.0f);
        atomicAdd(&packed[d], add);
    }
}

// Decode: dinv[i] = rsqrt(1 + sum*2^-32), cnt[i] = packed >> 44.
__global__ __launch_bounds__(256) void k_decode(const unsigned long long* __restrict__ packed,
                                                float* __restrict__ dinv,
                                                int* __restrict__ cnt, int n) {
    int i = blockIdx.x * 256 + threadIdx.x;
    if (i < n) {
        unsigned long long pv = packed[i];
        float deg = 1.0f + (float)(pv & ((1ULL << 44) - 1)) * (1.0f / 4294967296.0f);
        dinv[i] = rsqrtf(deg);
        cnt[i] = (int)(pv >> 44);
    }
    if (i == 0) cnt[n] = 0;
}

// Transpose + convert both weight matrices to bf16: WT[n][k] = bf16(W[k][n]).
__global__ __launch_bounds__(256) void k_cvtW(const float* __restrict__ W1,
                                              const float* __restrict__ W2,
                                              unsigned short* __restrict__ WT1,
                                              unsigned short* __restrict__ WT2) {
    int i = blockIdx.x * 256 + threadIdx.x;  // 16384 total
    int k = i >> 7, nn = i & 127;
    WT1[nn * 128 + k] = f2bf(W1[k * 128 + nn]);
    WT2[nn * 128 + k] = f2bf(W2[k * 128 + nn]);
}

// ---------------------------------------------------------------------------
// Hierarchical exclusive scan: out[i] = sum(in[0..i)).
// ---------------------------------------------------------------------------
__global__ __launch_bounds__(256) void k_scan1(const int* __restrict__ in,
                                               int* __restrict__ out,
                                               int* __restrict__ sums, int n) {
    __shared__ int s[256];
    const int t = threadIdx.x;
    const int base = blockIdx.x * 1024 + t * 4;
    int v0 = 0, v1 = 0, v2 = 0, v3 = 0;
    if (base + 0 < n) v0 = in[base + 0];
    if (base + 1 < n) v1 = in[base + 1];
    if (base + 2 < n) v2 = in[base + 2];
    if (base + 3 < n) v3 = in[base + 3];
    s[t] = v0 + v1 + v2 + v3;
    __syncthreads();
    #pragma unroll
    for (int off = 1; off < 256; off <<= 1) {
        int x = (t >= off) ? s[t - off] : 0;
        __syncthreads();
        s[t] += x;
        __syncthreads();
    }
    if (t == 255) sums[blockIdx.x] = s[255];
    int e = (t == 0) ? 0 : s[t - 1];
    if (base + 0 < n) out[base + 0] = e;
    if (base + 1 < n) out[base + 1] = e + v0;
    if (base + 2 < n) out[base + 2] = e + v0 + v1;
    if (base + 3 < n) out[base + 3] = e + v0 + v1 + v2;
}

__global__ __launch_bounds__(256) void k_scan2(int* __restrict__ sums, int g) {
    __shared__ int s[256];
    const int t = threadIdx.x;
    s[t] = (t < g) ? sums[t] : 0;
    __syncthreads();
    #pragma unroll
    for (int off = 1; off < 256; off <<= 1) {
        int x = (t >= off) ? s[t - off] : 0;
        __syncthreads();
        s[t] += x;
        __syncthreads();
    }
    if (t < g) sums[t] = (t == 0) ? 0 : s[t - 1];  // exclusive
}

__global__ __launch_bounds__(256) void k_scan3(int* __restrict__ out,
                                               const int* __restrict__ sums, int n) {
    const int base = blockIdx.x * 1024 + threadIdx.x * 4;
    const int add = sums[blockIdx.x];
    #pragma unroll
    for (int u = 0; u < 4; ++u)
        if (base + u < n) out[base + u] += add;
}

// Fill CSR: csr[pos] = (src, dinv[src]*ew*dinv[dst]). Uses rowptr as cursor;
// after this kernel rowptr[d] == end offset of node d (start = rowptr[d-1]).
__global__ __launch_bounds__(256) void k_fill(const int* __restrict__ src,
                                              const int* __restrict__ dst,
                                              const float* __restrict__ ew,
                                              const float* __restrict__ dinv,
                                              int* __restrict__ rowptr,
                                              float2* __restrict__ csr, int e) {
    int i = blockIdx.x * 256 + threadIdx.x;
    if (i < e) {
        int s = src[i], d = dst[i];
        float nrm = dinv[s] * ew[i] * dinv[d];
        int pos = atomicAdd(&rowptr[d], 1);
        csr[pos] = make_float2(__int_as_float(s), nrm);
    }
}

// ---------------------------------------------------------------------------
// MFMA GEMM: H[n x 128] (bf16) = A[n x 128] @ W[128 x 128].
// WT is bf16, transposed ([n][k]). 256 threads = 4 waves; each wave owns 32
// rows x 128 cols = 2 row-tiles x 8 col-tiles of 16x16, K=128 in 4 steps.
// AFP32: A is fp32 (converted inline) vs bf16.
// ---------------------------------------------------------------------------
template <int AFP32>
__global__ __launch_bounds__(256) void k_gemm(const void* __restrict__ Ap,
                                              const unsigned short* __restrict__ WT,
                                              unsigned short* __restrict__ H, int n) {
    const int lane = threadIdx.x & 63;
    const int wv   = threadIdx.x >> 6;
    const int quad = lane >> 4;
    const int l16  = lane & 15;
    const int m0   = blockIdx.x * 128 + wv * 32;
    f32x4 acc[2][8] = {};

    #pragma unroll
    for (int ks = 0; ks < 4; ++ks) {
        const int k0 = ks * 32 + quad * 8;
        bf16x8 a[2];
        #pragma unroll
        for (int rt = 0; rt < 2; ++rt) {
            int row = m0 + rt * 16 + l16;
            if (row >= n) row = n - 1;  // clamp; stores are guarded
            if (AFP32) {
                const float* Af = (const float*)Ap + (size_t)row * 128 + k0;
                float4 f0 = *(const float4*)(Af);
                float4 f1 = *(const float4*)(Af + 4);
                bf16x8 v;
                v[0] = (short)f2bf(f0.x); v[1] = (short)f2bf(f0.y);
                v[2] = (short)f2bf(f0.z); v[3] = (short)f2bf(f0.w);
                v[4] = (short)f2bf(f1.x); v[5] = (short)f2bf(f1.y);
                v[6] = (short)f2bf(f1.z); v[7] = (short)f2bf(f1.w);
                a[rt] = v;
            } else {
                const unsigned short* Ab = (const unsigned short*)Ap + (size_t)row * 128 + k0;
                a[rt] = *(const bf16x8*)Ab;
            }
        }
        #pragma unroll
        for (int ct = 0; ct < 8; ++ct) {
            bf16x8 b = *(const bf16x8*)(WT + (size_t)(ct * 16 + l16) * 128 + k0);
            acc[0][ct] = __builtin_amdgcn_mfma_f32_16x16x32_bf16(a[0], b, acc[0][ct], 0, 0, 0);
            acc[1][ct] = __builtin_amdgcn_mfma_f32_16x16x32_bf16(a[1], b, acc[1][ct], 0, 0, 0);
        }
    }

    // D layout: col = lane&15, row = quad*4 + reg  (m89-verified)
    #pragma unroll
    for (int rt = 0; rt < 2; ++rt) {
        #pragma unroll
        for (int r = 0; r < 4; ++r) {
            int row = m0 + rt * 16 + quad * 4 + r;
            if (row < n) {
                unsigned short* o = H + (size_t)row * 128 + l16;
                #pragma unroll
                for (int ct = 0; ct < 8; ++ct)
                    o[ct * 16] = f2bf(acc[rt][ct][r]);
            }
        }
    }
}

// ---------------------------------------------------------------------------
// CSR gather + bias + activation. One 64-lane wave per node, 2 bf16 features
// (one uint) per lane, 8 edges in flight, fp32 accumulation.
// ACT 0: relu, writes bf16 pair (feeds layer-2 MFMA GEMM).
// ACT 1: sigmoid, writes float2 (final output).
// ---------------------------------------------------------------------------
__device__ __forceinline__ float2 bf2_decode(uint32 u) {
    return make_float2(__uint_as_float(u << 16),
                       __uint_as_float(u & 0xFFFF0000u));
}

template <int ACT>
__global__ __launch_bounds__(128) void k_gather(const uint32* __restrict__ Hb,
                                                const float2* __restrict__ csr,
                                                const int* __restrict__ endp,
                                                const float* __restrict__ dinv,
                                                const float* __restrict__ bias,
                                                void* __restrict__ outp, int N) {
    int node = blockIdx.x * 2 + (threadIdx.x >> 6);
    if (node >= N) return;
    const int lane = threadIdx.x & 63;
    const int start = (node == 0) ? 0 : endp[node - 1];
    const int end = endp[node];

    // self-loop: ew=1, norm = dinv[node]^2
    float di = dinv[node];
    float2 hv = bf2_decode(Hb[(size_t)node * 64 + lane]);
    float2 acc = make_float2(hv.x * di * di, hv.y * di * di);

    int k = start;
    for (; k + 7 < end; k += 8) {  // 8 independent row loads in flight
        float2 c[8];
        uint32 hu[8];
        #pragma unroll
        for (int u = 0; u < 8; ++u) c[u] = csr[k + u];
        #pragma unroll
        for (int u = 0; u < 8; ++u)
            hu[u] = Hb[(size_t)__float_as_int(c[u].x) * 64 + lane];
        #pragma unroll
        for (int u = 0; u < 8; ++u) {
            float2 hh = bf2_decode(hu[u]);
            acc.x += hh.x * c[u].y;
            acc.y += hh.y * c[u].y;
        }
    }
    for (; k < end; ++k) {
        float2 c0 = csr[k];
        float2 h0 = bf2_decode(Hb[(size_t)__float_as_int(c0.x) * 64 + lane]);
        acc.x += h0.x * c0.y;
        acc.y += h0.y * c0.y;
    }

    int j = lane * 2;
    acc.x += bias[j];
    acc.y += bias[j + 1];
    if (ACT == 0) {
        acc.x = fmaxf(acc.x, 0.f);
        acc.y = fmaxf(acc.y, 0.f);
        ((uint32*)outp)[(size_t)node * 64 + lane] =
            (uint32)f2bf(acc.x) | ((uint32)f2bf(acc.y) << 16);
    } else {
        acc.x = 1.f / (1.f + expf(-acc.x));
        acc.y = 1.f / (1.f + expf(-acc.y));
        ((float2*)outp)[(size_t)node * 64 + lane] = acc;
    }
}

extern "C" void kernel_launch(void* const* d_in, const int* in_sizes, int n_in,
                              void* d_out, int out_size, void* d_ws, size_t ws_size,
                              hipStream_t stream) {
    const float* x  = (const float*)d_in[0];
    const int*   ei = (const int*)d_in[1];
    const float* ew = (const float*)d_in[2];
    const float* W1 = (const float*)d_in[3];
    const float* b1 = (const float*)d_in[4];
    const float* W2 = (const float*)d_in[5];
    const float* b2 = (const float*)d_in[6];

    const int N = in_sizes[0] / 128;
    const int E = in_sizes[2];
    const int* src = ei;
    const int* dst = ei + E;
    float* out = (float*)d_out;

    // Workspace layout (256B-aligned slabs):
    //   dinv [N] | cnt [N+1] | rowptr [N+1] | csums [1024] | WT1 | WT2 [128^2 bf16]
    //   | csr [E f2] | h [N*128 bf16] | g1 [N*128 bf16]  (packed u64 aliases g1:
    //   packed is dead after k_decode, long before gather-1 writes g1)
    auto align = [](size_t v) { return (v + 255) & ~(size_t)255; };
    char* p = (char*)d_ws;
    float*  dinv   = (float*)p;   p += align((size_t)N * 4);
    int*    cnt    = (int*)p;     p += align((size_t)(N + 1) * 4);
    int*    rowptr = (int*)p;     p += align((size_t)(N + 1) * 4);
    int*    csums  = (int*)p;     p += align((size_t)1024 * 4);
    unsigned short* WT1 = (unsigned short*)p; p += align((size_t)128 * 128 * 2);
    unsigned short* WT2 = (unsigned short*)p; p += align((size_t)128 * 128 * 2);
    float2* csr    = (float2*)p;  p += align((size_t)E * 8);
    unsigned short* h  = (unsigned short*)p; p += align((size_t)N * 128 * 2);
    unsigned short* g1 = (unsigned short*)p;
    unsigned long long* packed = (unsigned long long*)g1;  // alias (dead early)

    const int nbN = (N + 255) / 256;
    const int nbE = (E + 255) / 256;
    const int nScan = N + 1;
    const int gScan = (nScan + 1023) / 1024;
    const int gGemm = (N + 127) / 128;

    // --- CSR + normalization build (shared by both layers) ---
    hipMemsetAsync(packed, 0, (size_t)N * 8, stream);
    k_hist<<<nbE, 256, 0, stream>>>(dst, ew, packed, E);
    k_decode<<<nbN, 256, 0, stream>>>(packed, dinv, cnt, N);
    k_cvtW<<<64, 256, 0, stream>>>(W1, W2, WT1, WT2);
    k_scan1<<<gScan, 256, 0, stream>>>(cnt, rowptr, csums, nScan);
    k_scan2<<<1, 256, 0, stream>>>(csums, gScan);
    k_scan3<<<gScan, 256, 0, stream>>>(rowptr, csums, nScan);
    k_fill<<<nbE, 256, 0, stream>>>(src, dst, ew, dinv, rowptr, csr, E);

    // --- Layer 1: h = bf16(x@W1) ; g1 = bf16(relu(gather(h) + b1)) ---
    k_gemm<1><<<gGemm, 256, 0, stream>>>(x, WT1, h, N);
    k_gather<0><<<(N + 1) / 2, 128, 0, stream>>>((const uint32*)h, csr, rowptr,
                                                 dinv, b1, g1, N);

    // --- Layer 2: h = bf16(g1@W2) ; out = sigmoid(gather(h) + b2) ---
    k_gemm<0><<<gGemm, 256, 0, stream>>>(g1, WT2, h, N);
    k_gather<1><<<(N + 1) / 2, 128, 0, stream>>>((const uint32*)h, csr, rowptr,
                                                 dinv, b2, out, N);
}

// Round 8
// 243.038 us; speedup vs baseline: 3.4016x; 1.0869x over previous
//
#include <hip/hip_runtime.h>
#include <math.h>

// ---------------------------------------------------------------------------
// GCN 2-layer forward on MI355X.
// Round 8: CSR build streamlined. k_hist's packed u64 atomicAdd RETURN value
// gives each edge's rank within its dst segment (old>>44) -> k_fill becomes
// atomic-free (pos = rowptr[d] + rank[e]). k_decode fused into k_scan1.
// rowptr stays a clean exclusive scan; gather tail is predicated batches of 8.
// ---------------------------------------------------------------------------

typedef unsigned int uint32;
typedef __attribute__((ext_vector_type(8))) short bf16x8;   // 8 bf16 (4 VGPRs)
typedef __attribute__((ext_vector_type(4))) float f32x4;

__device__ __forceinline__ unsigned short f2bf(float f) {   // RNE fp32->bf16
    uint32 b = __float_as_uint(f);
    return (unsigned short)((b + 0x7FFFu + ((b >> 16) & 1u)) >> 16);
}

// One u64 atomic per edge: +1 in the count field (bits 44+), +ew in Q.32 sum.
// The returned old value's count field is this edge's rank within its dst.
__global__ __launch_bounds__(256) void k_hist(const int* __restrict__ dst,
                                              const float* __restrict__ ew,
                                              unsigned long long* __restrict__ packed,
                                              int* __restrict__ rank, int e) {
    int i = blockIdx.x * 256 + threadIdx.x;
    if (i < e) {
        int d = dst[i];
        unsigned long long add =
            (1ULL << 44) + (unsigned long long)(ew[i] * 4294967296.0f);
        unsigned long long old = atomicAdd(&packed[d], add);
        rank[i] = (int)(old >> 44);
    }
}

// Transpose + convert both weight matrices to bf16: WT[n][k] = bf16(W[k][n]).
__global__ __launch_bounds__(256) void k_cvtW(const float* __restrict__ W1,
                                              const float* __restrict__ W2,
                                              unsigned short* __restrict__ WT1,
                                              unsigned short* __restrict__ WT2) {
    int i = blockIdx.x * 256 + threadIdx.x;  // 16384 total
    int k = i >> 7, nn = i & 127;
    WT1[nn * 128 + k] = f2bf(W1[k * 128 + nn]);
    WT2[nn * 128 + k] = f2bf(W2[k * 128 + nn]);
}

// ---------------------------------------------------------------------------
// Hierarchical exclusive scan over cnt(packed) with fused decode:
// pass 1 reads packed[], extracts cnt, emits local excl. scan + chunk sums,
// and writes dinv[i] = rsqrt(1 + ewsum*2^-32) along the way.
// ---------------------------------------------------------------------------
__global__ __launch_bounds__(256) void k_scan1(const unsigned long long* __restrict__ packed,
                                               float* __restrict__ dinv,
                                               int* __restrict__ out,
                                               int* __restrict__ sums, int nNodes) {
    __shared__ int s[256];
    const int t = threadIdx.x;
    const int base = blockIdx.x * 1024 + t * 4;
    const int n = nNodes + 1;  // scan domain: N counts + trailing 0
    int v[4];
    #pragma unroll
    for (int u = 0; u < 4; ++u) {
        int idx = base + u;
        int c = 0;
        if (idx < nNodes) {
            unsigned long long pv = packed[idx];
            c = (int)(pv >> 44);
            float deg = 1.0f + (float)(pv & ((1ULL << 44) - 1)) * (1.0f / 4294967296.0f);
            dinv[idx] = rsqrtf(deg);
        }
        v[u] = c;
    }
    s[t] = v[0] + v[1] + v[2] + v[3];
    __syncthreads();
    #pragma unroll
    for (int off = 1; off < 256; off <<= 1) {
        int x = (t >= off) ? s[t - off] : 0;
        __syncthreads();
        s[t] += x;
        __syncthreads();
    }
    if (t == 255) sums[blockIdx.x] = s[255];
    int e = (t == 0) ? 0 : s[t - 1];
    if (base + 0 < n) out[base + 0] = e;
    if (base + 1 < n) out[base + 1] = e + v[0];
    if (base + 2 < n) out[base + 2] = e + v[0] + v[1];
    if (base + 3 < n) out[base + 3] = e + v[0] + v[1] + v[2];
}

__global__ __launch_bounds__(256) void k_scan2(int* __restrict__ sums, int g) {
    __shared__ int s[256];
    const int t = threadIdx.x;
    s[t] = (t < g) ? sums[t] : 0;
    __syncthreads();
    #pragma unroll
    for (int off = 1; off < 256; off <<= 1) {
        int x = (t >= off) ? s[t - off] : 0;
        __syncthreads();
        s[t] += x;
        __syncthreads();
    }
    if (t < g) sums[t] = (t == 0) ? 0 : s[t - 1];  // exclusive
}

__global__ __launch_bounds__(256) void k_scan3(int* __restrict__ out,
                                               const int* __restrict__ sums, int n) {
    const int base = blockIdx.x * 1024 + threadIdx.x * 4;
    const int add = sums[blockIdx.x];
    #pragma unroll
    for (int u = 0; u < 4; ++u)
        if (base + u < n) out[base + u] += add;
}

// Fill CSR (atomic-free): csr[rowptr[d] + rank[e]] = (src, dinv[s]*ew*dinv[d]).
__global__ __launch_bounds__(256) void k_fill(const int* __restrict__ src,
                                              const int* __restrict__ dst,
                                              const float* __restrict__ ew,
                                              const float* __restrict__ dinv,
                                              const int* __restrict__ rowptr,
                                              const int* __restrict__ rank,
                                              float2* __restrict__ csr, int e) {
    int i = blockIdx.x * 256 + threadIdx.x;
    if (i < e) {
        int s = src[i], d = dst[i];
        float nrm = dinv[s] * ew[i] * dinv[d];
        int pos = rowptr[d] + rank[i];
        csr[pos] = make_float2(__int_as_float(s), nrm);
    }
}

// ---------------------------------------------------------------------------
// MFMA GEMM: H[n x 128] (bf16) = A[n x 128] @ W[128 x 128].
// WT is bf16, transposed ([n][k]). 256 threads = 4 waves; each wave owns 32
// rows x 128 cols = 2 row-tiles x 8 col-tiles of 16x16, K=128 in 4 steps.
// AFP32: A is fp32 (converted inline) vs bf16.
// ---------------------------------------------------------------------------
template <int AFP32>
__global__ __launch_bounds__(256) void k_gemm(const void* __restrict__ Ap,
                                              const unsigned short* __restrict__ WT,
                                              unsigned short* __restrict__ H, int n) {
    const int lane = threadIdx.x & 63;
    const int wv   = threadIdx.x >> 6;
    const int quad = lane >> 4;
    const int l16  = lane & 15;
    const int m0   = blockIdx.x * 128 + wv * 32;
    f32x4 acc[2][8] = {};

    #pragma unroll
    for (int ks = 0; ks < 4; ++ks) {
        const int k0 = ks * 32 + quad * 8;
        bf16x8 a[2];
        #pragma unroll
        for (int rt = 0; rt < 2; ++rt) {
            int row = m0 + rt * 16 + l16;
            if (row >= n) row = n - 1;  // clamp; stores are guarded
            if (AFP32) {
                const float* Af = (const float*)Ap + (size_t)row * 128 + k0;
                float4 f0 = *(const float4*)(Af);
                float4 f1 = *(const float4*)(Af + 4);
                bf16x8 v;
                v[0] = (short)f2bf(f0.x); v[1] = (short)f2bf(f0.y);
                v[2] = (short)f2bf(f0.z); v[3] = (short)f2bf(f0.w);
                v[4] = (short)f2bf(f1.x); v[5] = (short)f2bf(f1.y);
                v[6] = (short)f2bf(f1.z); v[7] = (short)f2bf(f1.w);
                a[rt] = v;
            } else {
                const unsigned short* Ab = (const unsigned short*)Ap + (size_t)row * 128 + k0;
                a[rt] = *(const bf16x8*)Ab;
            }
        }
        #pragma unroll
        for (int ct = 0; ct < 8; ++ct) {
            bf16x8 b = *(const bf16x8*)(WT + (size_t)(ct * 16 + l16) * 128 + k0);
            acc[0][ct] = __builtin_amdgcn_mfma_f32_16x16x32_bf16(a[0], b, acc[0][ct], 0, 0, 0);
            acc[1][ct] = __builtin_amdgcn_mfma_f32_16x16x32_bf16(a[1], b, acc[1][ct], 0, 0, 0);
        }
    }

    // D layout: col = lane&15, row = quad*4 + reg  (m89-verified)
    #pragma unroll
    for (int rt = 0; rt < 2; ++rt) {
        #pragma unroll
        for (int r = 0; r < 4; ++r) {
            int row = m0 + rt * 16 + quad * 4 + r;
            if (row < n) {
                unsigned short* o = H + (size_t)row * 128 + l16;
                #pragma unroll
                for (int ct = 0; ct < 8; ++ct)
                    o[ct * 16] = f2bf(acc[rt][ct][r]);
            }
        }
    }
}

// ---------------------------------------------------------------------------
// CSR gather + bias + activation. One 64-lane wave per node, 2 bf16 features
// (one uint) per lane, predicated batches of 8 edges in flight (no serial
// tail), fp32 accumulation.
// ACT 0: relu, writes bf16 pair (feeds layer-2 MFMA GEMM).
// ACT 1: sigmoid, writes float2 (final output).
// ---------------------------------------------------------------------------
__device__ __forceinline__ float2 bf2_decode(uint32 u) {
    return make_float2(__uint_as_float(u << 16),
                       __uint_as_float(u & 0xFFFF0000u));
}

template <int ACT>
__global__ __launch_bounds__(128) void k_gather(const uint32* __restrict__ Hb,
                                                const float2* __restrict__ csr,
                                                const int* __restrict__ rowptr,
                                                const float* __restrict__ dinv,
                                                const float* __restrict__ bias,
                                                void* __restrict__ outp, int N) {
    int node = blockIdx.x * 2 + (threadIdx.x >> 6);
    if (node >= N) return;
    const int lane = threadIdx.x & 63;
    const int start = rowptr[node];
    const int end = rowptr[node + 1];

    // self-loop: ew=1, norm = dinv[node]^2
    float di = dinv[node];
    float2 hv = bf2_decode(Hb[(size_t)node * 64 + lane]);
    float2 acc = make_float2(hv.x * di * di, hv.y * di * di);

    for (int k = start; k < end; k += 8) {  // predicated batch: 8 loads in flight
        float2 c[8];
        uint32 hu[8];
        #pragma unroll
        for (int u = 0; u < 8; ++u) {
            int kk = k + u;
            c[u] = csr[kk < end ? kk : end - 1];
            if (kk >= end) c[u].y = 0.0f;  // OOB lanes contribute nothing
        }
        #pragma unroll
        for (int u = 0; u < 8; ++u)
            hu[u] = Hb[(size_t)__float_as_int(c[u].x) * 64 + lane];
        #pragma unroll
        for (int u = 0; u < 8; ++u) {
            float2 hh = bf2_decode(hu[u]);
            acc.x += hh.x * c[u].y;
            acc.y += hh.y * c[u].y;
        }
    }

    int j = lane * 2;
    acc.x += bias[j];
    acc.y += bias[j + 1];
    if (ACT == 0) {
        acc.x = fmaxf(acc.x, 0.f);
        acc.y = fmaxf(acc.y, 0.f);
        ((uint32*)outp)[(size_t)node * 64 + lane] =
            (uint32)f2bf(acc.x) | ((uint32)f2bf(acc.y) << 16);
    } else {
        acc.x = 1.f / (1.f + expf(-acc.x));
        acc.y = 1.f / (1.f + expf(-acc.y));
        ((float2*)outp)[(size_t)node * 64 + lane] = acc;
    }
}

extern "C" void kernel_launch(void* const* d_in, const int* in_sizes, int n_in,
                              void* d_out, int out_size, void* d_ws, size_t ws_size,
                              hipStream_t stream) {
    const float* x  = (const float*)d_in[0];
    const int*   ei = (const int*)d_in[1];
    const float* ew = (const float*)d_in[2];
    const float* W1 = (const float*)d_in[3];
    const float* b1 = (const float*)d_in[4];
    const float* W2 = (const float*)d_in[5];
    const float* b2 = (const float*)d_in[6];

    const int N = in_sizes[0] / 128;
    const int E = in_sizes[2];
    const int* src = ei;
    const int* dst = ei + E;
    float* out = (float*)d_out;

    // Workspace layout (256B-aligned slabs):
    //   dinv [N] | rowptr [N+1] | csums [1024] | WT1 | WT2 [128^2 bf16]
    //   | rank [E i32] | csr [E f2] | h [N*128 bf16] | g1 [N*128 bf16]
    //   (packed u64 aliases g1: dead after k_scan1, g1 written at gather-1)
    auto align = [](size_t v) { return (v + 255) & ~(size_t)255; };
    char* p = (char*)d_ws;
    float*  dinv   = (float*)p;   p += align((size_t)N * 4);
    int*    rowptr = (int*)p;     p += align((size_t)(N + 1) * 4);
    int*    csums  = (int*)p;     p += align((size_t)1024 * 4);
    unsigned short* WT1 = (unsigned short*)p; p += align((size_t)128 * 128 * 2);
    unsigned short* WT2 = (unsigned short*)p; p += align((size_t)128 * 128 * 2);
    int*    rank   = (int*)p;     p += align((size_t)E * 4);
    float2* csr    = (float2*)p;  p += align((size_t)E * 8);
    unsigned short* h  = (unsigned short*)p; p += align((size_t)N * 128 * 2);
    unsigned short* g1 = (unsigned short*)p;
    unsigned long long* packed = (unsigned long long*)g1;  // alias (dead early)

    const int nbE = (E + 255) / 256;
    const int nScan = N + 1;
    const int gScan = (nScan + 1023) / 1024;
    const int gGemm = (N + 127) / 128;

    // --- CSR + normalization build (shared by both layers) ---
    hipMemsetAsync(packed, 0, (size_t)N * 8, stream);
    k_hist<<<nbE, 256, 0, stream>>>(dst, ew, packed, rank, E);
    k_cvtW<<<64, 256, 0, stream>>>(W1, W2, WT1, WT2);
    k_scan1<<<gScan, 256, 0, stream>>>(packed, dinv, rowptr, csums, N);
    k_scan2<<<1, 256, 0, stream>>>(csums, gScan);
    k_scan3<<<gScan, 256, 0, stream>>>(rowptr, csums, nScan);
    k_fill<<<nbE, 256, 0, stream>>>(src, dst, ew, dinv, rowptr, rank, csr, E);

    // --- Layer 1: h = bf16(x@W1) ; g1 = bf16(relu(gather(h) + b1)) ---
    k_gemm<1><<<gGemm, 256, 0, stream>>>(x, WT1, h, N);
    k_gather<0><<<(N + 1) / 2, 128, 0, stream>>>((const uint32*)h, csr, rowptr,
                                                 dinv, b1, g1, N);

    // --- Layer 2: h = bf16(g1@W2) ; out = sigmoid(gather(h) + b2) ---
    k_gemm<0><<<gGemm, 256, 0, stream>>>(g1, WT2, h, N);
    k_gather<1><<<(N + 1) / 2, 128, 0, stream>>>((const uint32*)h, csr, rowptr,
                                                 dinv, b2, out, N);
}

// Round 9
// 230.477 us; speedup vs baseline: 3.5870x; 1.0545x over previous
//
#include <hip/hip_runtime.h>
#include <math.h>

// ---------------------------------------------------------------------------
// GCN 2-layer forward on MI355X.
// Round 9: (1) gather -> quarter-wave uint4 row loads (16 lanes x 16 B per
// row; one vmem inst covers 4 rows) + cross-quarter shuffle reduction;
// (2) k_hist 4-way replicated histograms (cuts same-address atomic collision
// density 4x; per-replica ranks re-based via packed u64 bases[]);
// (3) scan3 folded into fill/gather, cvtW folded into hist's grid (9 launches).
// ---------------------------------------------------------------------------

typedef unsigned int uint32;
typedef unsigned long long u64;
typedef __attribute__((ext_vector_type(8))) short bf16x8;   // 8 bf16 (4 VGPRs)
typedef __attribute__((ext_vector_type(4))) float f32x4;

__device__ __forceinline__ unsigned short f2bf(float f) {   // RNE fp32->bf16
    uint32 b = __float_as_uint(f);
    return (unsigned short)((b + 0x7FFFu + ((b >> 16) & 1u)) >> 16);
}

__device__ __forceinline__ float2 bf2_decode(uint32 u) {
    return make_float2(__uint_as_float(u << 16),
                       __uint_as_float(u & 0xFFFF0000u));
}

// ---------------------------------------------------------------------------
// Hist (4-replica) + folded-in weight transpose/convert.
// Blocks [0,nbE): one u64 atomic per edge into replica (blockIdx&3):
//   +1 in bits 44+, +ew in Q.32 low bits. Returned old>>44 = per-replica rank.
// Blocks [nbE, nbE+64): WT[n][k] = bf16(W[k][n]) for both layers.
// ---------------------------------------------------------------------------
__global__ __launch_bounds__(256) void k_hist(const int* __restrict__ dst,
                                              const float* __restrict__ ew,
                                              u64* __restrict__ packed,
                                              int* __restrict__ rank, int e, int nNodes,
                                              const float* __restrict__ W1,
                                              const float* __restrict__ W2,
                                              unsigned short* __restrict__ WT1,
                                              unsigned short* __restrict__ WT2,
                                              int nbE) {
    const int b = blockIdx.x;
    if (b >= nbE) {  // weight transpose+convert lane
        int j = (b - nbE) * 256 + threadIdx.x;  // 16384 total
        int k = j >> 7, nn = j & 127;
        WT1[nn * 128 + k] = f2bf(W1[k * 128 + nn]);
        WT2[nn * 128 + k] = f2bf(W2[k * 128 + nn]);
        return;
    }
    int i = b * 256 + threadIdx.x;
    if (i < e) {
        int d = dst[i];
        int r = b & 3;
        u64 add = (1ULL << 44) + (u64)(ew[i] * 4294967296.0f);
        u64 old = atomicAdd(&packed[(size_t)r * nNodes + d], add);
        rank[i] = (int)(old >> 44);
    }
}

// ---------------------------------------------------------------------------
// Scan pass 1 with fused decode: reads the 4 replicas, emits
//   dinv[i]  = rsqrt(1 + total_ewsum * 2^-32)
//   bases[i] = per-replica exclusive offsets (4 x 16-bit packed)
//   out[]    = per-1024-chunk local exclusive scan of total counts
//   sums[]   = chunk totals.
// ---------------------------------------------------------------------------
__global__ __launch_bounds__(256) void k_scan1(const u64* __restrict__ packed,
                                               float* __restrict__ dinv,
                                               u64* __restrict__ bases,
                                               int* __restrict__ out,
                                               int* __restrict__ sums, int nNodes) {
    __shared__ int s[256];
    const int t = threadIdx.x;
    const int base = blockIdx.x * 1024 + t * 4;
    const int n = nNodes + 1;  // scan domain: N counts + trailing 0
    int v[4];
    #pragma unroll
    for (int u = 0; u < 4; ++u) {
        int idx = base + u;
        int c = 0;
        if (idx < nNodes) {
            const u64 mask = (1ULL << 44) - 1;
            u64 p0 = packed[idx];
            u64 p1 = packed[(size_t)nNodes + idx];
            u64 p2 = packed[2 * (size_t)nNodes + idx];
            u64 p3 = packed[3 * (size_t)nNodes + idx];
            uint32 c0 = (uint32)(p0 >> 44), c1 = (uint32)(p1 >> 44);
            uint32 c2 = (uint32)(p2 >> 44), c3 = (uint32)(p3 >> 44);
            c = (int)(c0 + c1 + c2 + c3);
            u64 ssum = (p0 & mask) + (p1 & mask) + (p2 & mask) + (p3 & mask);
            float deg = 1.0f + (float)ssum * (1.0f / 4294967296.0f);
            dinv[idx] = rsqrtf(deg);
            bases[idx] = ((u64)c0 << 16) | ((u64)(c0 + c1) << 32)
                       | ((u64)(c0 + c1 + c2) << 48);  // base for replica 0 = 0
        }
        v[u] = c;
    }
    s[t] = v[0] + v[1] + v[2] + v[3];
    __syncthreads();
    #pragma unroll
    for (int off = 1; off < 256; off <<= 1) {
        int x = (t >= off) ? s[t - off] : 0;
        __syncthreads();
        s[t] += x;
        __syncthreads();
    }
    if (t == 255) sums[blockIdx.x] = s[255];
    int e = (t == 0) ? 0 : s[t - 1];
    if (base + 0 < n) out[base + 0] = e;
    if (base + 1 < n) out[base + 1] = e + v[0];
    if (base + 2 < n) out[base + 2] = e + v[0] + v[1];
    if (base + 3 < n) out[base + 3] = e + v[0] + v[1] + v[2];
}

__global__ __launch_bounds__(256) void k_scan2(int* __restrict__ sums, int g) {
    __shared__ int s[256];
    const int t = threadIdx.x;
    s[t] = (t < g) ? sums[t] : 0;
    __syncthreads();
    #pragma unroll
    for (int off = 1; off < 256; off <<= 1) {
        int x = (t >= off) ? s[t - off] : 0;
        __syncthreads();
        s[t] += x;
        __syncthreads();
    }
    if (t < g) sums[t] = (t == 0) ? 0 : s[t - 1];  // exclusive
}

// Fill CSR (atomic-free):
//   pos = rowptr_local[d] + csums[d>>10] + base_replica(d, r) + rank[e].
__global__ __launch_bounds__(256) void k_fill(const int* __restrict__ src,
                                              const int* __restrict__ dst,
                                              const float* __restrict__ ew,
                                              const float* __restrict__ dinv,
                                              const int* __restrict__ rowptr,
                                              const int* __restrict__ csums,
                                              const u64* __restrict__ bases,
                                              const int* __restrict__ rank,
                                              float2* __restrict__ csr, int e) {
    int i = blockIdx.x * 256 + threadIdx.x;
    if (i < e) {
        int s = src[i], d = dst[i];
        int r = blockIdx.x & 3;  // must match k_hist's replica map
        float nrm = dinv[s] * ew[i] * dinv[d];
        int pos = rowptr[d] + csums[d >> 10]
                + (int)((bases[d] >> (16 * r)) & 0xFFFF) + rank[i];
        csr[pos] = make_float2(__int_as_float(s), nrm);
    }
}

// ---------------------------------------------------------------------------
// MFMA GEMM: H[n x 128] (bf16) = A[n x 128] @ W[128 x 128].
// WT is bf16, transposed ([n][k]). 256 threads = 4 waves; each wave owns 32
// rows x 128 cols = 2 row-tiles x 8 col-tiles of 16x16, K=128 in 4 steps.
// AFP32: A is fp32 (converted inline) vs bf16.
// ---------------------------------------------------------------------------
template <int AFP32>
__global__ __launch_bounds__(256) void k_gemm(const void* __restrict__ Ap,
                                              const unsigned short* __restrict__ WT,
                                              unsigned short* __restrict__ H, int n) {
    const int lane = threadIdx.x & 63;
    const int wv   = threadIdx.x >> 6;
    const int quad = lane >> 4;
    const int l16  = lane & 15;
    const int m0   = blockIdx.x * 128 + wv * 32;
    f32x4 acc[2][8] = {};

    #pragma unroll
    for (int ks = 0; ks < 4; ++ks) {
        const int k0 = ks * 32 + quad * 8;
        bf16x8 a[2];
        #pragma unroll
        for (int rt = 0; rt < 2; ++rt) {
            int row = m0 + rt * 16 + l16;
            if (row >= n) row = n - 1;  // clamp; stores are guarded
            if (AFP32) {
                const float* Af = (const float*)Ap + (size_t)row * 128 + k0;
                float4 f0 = *(const float4*)(Af);
                float4 f1 = *(const float4*)(Af + 4);
                bf16x8 v;
                v[0] = (short)f2bf(f0.x); v[1] = (short)f2bf(f0.y);
                v[2] = (short)f2bf(f0.z); v[3] = (short)f2bf(f0.w);
                v[4] = (short)f2bf(f1.x); v[5] = (short)f2bf(f1.y);
                v[6] = (short)f2bf(f1.z); v[7] = (short)f2bf(f1.w);
                a[rt] = v;
            } else {
                const unsigned short* Ab = (const unsigned short*)Ap + (size_t)row * 128 + k0;
                a[rt] = *(const bf16x8*)Ab;
            }
        }
        #pragma unroll
        for (int ct = 0; ct < 8; ++ct) {
            bf16x8 b = *(const bf16x8*)(WT + (size_t)(ct * 16 + l16) * 128 + k0);
            acc[0][ct] = __builtin_amdgcn_mfma_f32_16x16x32_bf16(a[0], b, acc[0][ct], 0, 0, 0);
            acc[1][ct] = __builtin_amdgcn_mfma_f32_16x16x32_bf16(a[1], b, acc[1][ct], 0, 0, 0);
        }
    }

    // D layout: col = lane&15, row = quad*4 + reg  (m89-verified)
    #pragma unroll
    for (int rt = 0; rt < 2; ++rt) {
        #pragma unroll
        for (int r = 0; r < 4; ++r) {
            int row = m0 + rt * 16 + quad * 4 + r;
            if (row < n) {
                unsigned short* o = H + (size_t)row * 128 + l16;
                #pragma unroll
                for (int ct = 0; ct < 8; ++ct)
                    o[ct * 16] = f2bf(acc[rt][ct][r]);
            }
        }
    }
}

// ---------------------------------------------------------------------------
// CSR gather, quarter-wave layout: one 64-lane wave per node; each 16-lane
// quarter reads a full 256 B bf16 row as uint4 (16 B/lane). Per iteration the
// wave covers 8 edges (2 per quarter) in 2 vmem instructions. Partial sums
// are combined across quarters with __shfl_xor(16/32). fp32 accumulation.
// ACT 0: relu -> bf16 row (feeds layer-2 MFMA). ACT 1: sigmoid -> fp32 row.
// ---------------------------------------------------------------------------
__device__ __forceinline__ void fma8(float* acc, uint4 u, float w) {
    float2 f;
    f = bf2_decode(u.x); acc[0] += f.x * w; acc[1] += f.y * w;
    f = bf2_decode(u.y); acc[2] += f.x * w; acc[3] += f.y * w;
    f = bf2_decode(u.z); acc[4] += f.x * w; acc[5] += f.y * w;
    f = bf2_decode(u.w); acc[6] += f.x * w; acc[7] += f.y * w;
}

template <int ACT>
__global__ __launch_bounds__(256) void k_gather(const uint4* __restrict__ Hb4,
                                                const float2* __restrict__ csr,
                                                const int* __restrict__ rowptr,
                                                const int* __restrict__ csums,
                                                const float* __restrict__ dinv,
                                                const float4* __restrict__ bias4,
                                                void* __restrict__ outp, int N) {
    int node = blockIdx.x * 4 + (threadIdx.x >> 6);
    if (node >= N) return;
    const int lane = threadIdx.x & 63;
    const int q = lane >> 4, l = lane & 15;
    const int start = rowptr[node] + csums[node >> 10];
    const int end   = rowptr[node + 1] + csums[(node + 1) >> 10];

    // self-loop (ew=1, norm=dinv^2): counted once, via quarter 0 only
    float di = dinv[node];
    float selfw = (q == 0) ? di * di : 0.0f;
    float acc[8] = {};
    fma8(acc, Hb4[(size_t)node * 16 + l], selfw);

    for (int k = start; k < end; k += 8) {  // 8 edges/iter across quarters
        int e0 = k + q, e1 = k + q + 4;
        float2 c0 = csr[e0 < end ? e0 : end - 1];
        float2 c1 = csr[e1 < end ? e1 : end - 1];
        float w0 = (e0 < end) ? c0.y : 0.0f;
        float w1 = (e1 < end) ? c1.y : 0.0f;
        uint4 u0 = Hb4[(size_t)__float_as_int(c0.x) * 16 + l];
        uint4 u1 = Hb4[(size_t)__float_as_int(c1.x) * 16 + l];
        fma8(acc, u0, w0);
        fma8(acc, u1, w1);
    }

    // combine quarters: after xor-16 and xor-32 every lane holds the total
    #pragma unroll
    for (int j = 0; j < 8; ++j) {
        acc[j] += __shfl_xor(acc[j], 16, 64);
        acc[j] += __shfl_xor(acc[j], 32, 64);
    }

    if (q == 0) {  // lanes 0..15 write the row
        float4 b0 = bias4[l * 2], b1 = bias4[l * 2 + 1];
        acc[0] += b0.x; acc[1] += b0.y; acc[2] += b0.z; acc[3] += b0.w;
        acc[4] += b1.x; acc[5] += b1.y; acc[6] += b1.z; acc[7] += b1.w;
        if (ACT == 0) {
            #pragma unroll
            for (int j = 0; j < 8; ++j) acc[j] = fmaxf(acc[j], 0.0f);
            uint4 o;
            o.x = (uint32)f2bf(acc[0]) | ((uint32)f2bf(acc[1]) << 16);
            o.y = (uint32)f2bf(acc[2]) | ((uint32)f2bf(acc[3]) << 16);
            o.z = (uint32)f2bf(acc[4]) | ((uint32)f2bf(acc[5]) << 16);
            o.w = (uint32)f2bf(acc[6]) | ((uint32)f2bf(acc[7]) << 16);
            ((uint4*)outp)[(size_t)node * 16 + l] = o;
        } else {
            #pragma unroll
            for (int j = 0; j < 8; ++j) acc[j] = 1.0f / (1.0f + expf(-acc[j]));
            float4* o4 = (float4*)outp + (size_t)node * 32 + l * 2;
            o4[0] = make_float4(acc[0], acc[1], acc[2], acc[3]);
            o4[1] = make_float4(acc[4], acc[5], acc[6], acc[7]);
        }
    }
}

extern "C" void kernel_launch(void* const* d_in, const int* in_sizes, int n_in,
                              void* d_out, int out_size, void* d_ws, size_t ws_size,
                              hipStream_t stream) {
    const float* x  = (const float*)d_in[0];
    const int*   ei = (const int*)d_in[1];
    const float* ew = (const float*)d_in[2];
    const float* W1 = (const float*)d_in[3];
    const float* b1 = (const float*)d_in[4];
    const float* W2 = (const float*)d_in[5];
    const float* b2 = (const float*)d_in[6];

    const int N = in_sizes[0] / 128;
    const int E = in_sizes[2];
    const int* src = ei;
    const int* dst = ei + E;
    float* out = (float*)d_out;

    // Workspace layout (256B-aligned slabs):
    //   dinv [N] | rowptr [N+1] | csums [1024] | bases [N u64] | WT1 | WT2
    //   | rank [E] | csr [E f2] | h [N*128 bf16] | g1 [N*128 bf16]
    //   (packed u64[4N] aliases g1: dead after k_scan1, g1 written at gather-1)
    auto align = [](size_t v) { return (v + 255) & ~(size_t)255; };
    char* p = (char*)d_ws;
    float*  dinv   = (float*)p;   p += align((size_t)N * 4);
    int*    rowptr = (int*)p;     p += align((size_t)(N + 1) * 4);
    int*    csums  = (int*)p;     p += align((size_t)1024 * 4);
    u64*    bases  = (u64*)p;     p += align((size_t)N * 8);
    unsigned short* WT1 = (unsigned short*)p; p += align((size_t)128 * 128 * 2);
    unsigned short* WT2 = (unsigned short*)p; p += align((size_t)128 * 128 * 2);
    int*    rank   = (int*)p;     p += align((size_t)E * 4);
    float2* csr    = (float2*)p;  p += align((size_t)E * 8);
    unsigned short* h  = (unsigned short*)p; p += align((size_t)N * 128 * 2);
    unsigned short* g1 = (unsigned short*)p;
    u64* packed = (u64*)g1;  // alias (dead after scan1)

    const int nbE = (E + 255) / 256;
    const int gScan = (N + 1 + 1023) / 1024;
    const int gGemm = (N + 127) / 128;
    const int gGath = (N + 3) / 4;

    // --- CSR + normalization build (shared by both layers) ---
    hipMemsetAsync(packed, 0, (size_t)4 * N * 8, stream);
    k_hist<<<nbE + 64, 256, 0, stream>>>(dst, ew, packed, rank, E, N,
                                         W1, W2, WT1, WT2, nbE);
    k_scan1<<<gScan, 256, 0, stream>>>(packed, dinv, bases, rowptr, csums, N);
    k_scan2<<<1, 256, 0, stream>>>(csums, gScan);
    k_fill<<<nbE, 256, 0, stream>>>(src, dst, ew, dinv, rowptr, csums, bases,
                                    rank, csr, E);

    // --- Layer 1: h = bf16(x@W1) ; g1 = bf16(relu(gather(h) + b1)) ---
    k_gemm<1><<<gGemm, 256, 0, stream>>>(x, WT1, h, N);
    k_gather<0><<<gGath, 256, 0, stream>>>((const uint4*)h, csr, rowptr, csums,
                                           dinv, (const float4*)b1, g1, N);

    // --- Layer 2: h = bf16(g1@W2) ; out = sigmoid(gather(h) + b2) ---
    k_gemm<0><<<gGemm, 256, 0, stream>>>(g1, WT2, h, N);
    k_gather<1><<<gGath, 256, 0, stream>>>((const uint4*)h, csr, rowptr, csums,
                                           dinv, (const float4*)b2, out, N);
}

// Round 10
// 227.790 us; speedup vs baseline: 3.6293x; 1.0118x over previous
//
#include <hip/hip_runtime.h>
#include <math.h>

// ---------------------------------------------------------------------------
// GCN 2-layer forward on MI355X.
// Round 10: (1) gather inner loop 8 -> 16 edges/iter (4 row-loads in flight
// per 16-lane quarter; typical node = ONE iteration) — gather is latency-
// bound (VALU total ~5 us vs ~25 us measured), more MLP is the fix;
// (2) hist 4 -> 8 replicas (collision density halved; per-replica bases
// packed 8x8-bit). Everything else unchanged from R9.
// ---------------------------------------------------------------------------

typedef unsigned int uint32;
typedef unsigned long long u64;
typedef __attribute__((ext_vector_type(8))) short bf16x8;   // 8 bf16 (4 VGPRs)
typedef __attribute__((ext_vector_type(4))) float f32x4;

__device__ __forceinline__ unsigned short f2bf(float f) {   // RNE fp32->bf16
    uint32 b = __float_as_uint(f);
    return (unsigned short)((b + 0x7FFFu + ((b >> 16) & 1u)) >> 16);
}

__device__ __forceinline__ float2 bf2_decode(uint32 u) {
    return make_float2(__uint_as_float(u << 16),
                       __uint_as_float(u & 0xFFFF0000u));
}

// ---------------------------------------------------------------------------
// Hist (8-replica) + folded-in weight transpose/convert.
// Blocks [0,nbE): one u64 atomic per edge into replica (blockIdx&7):
//   +1 in bits 44+, +ew in Q.32 low bits. Returned old>>44 = per-replica rank.
// Blocks [nbE, nbE+64): WT[n][k] = bf16(W[k][n]) for both layers.
// ---------------------------------------------------------------------------
__global__ __launch_bounds__(256) void k_hist(const int* __restrict__ dst,
                                              const float* __restrict__ ew,
                                              u64* __restrict__ packed,
                                              int* __restrict__ rank, int e, int nNodes,
                                              const float* __restrict__ W1,
                                              const float* __restrict__ W2,
                                              unsigned short* __restrict__ WT1,
                                              unsigned short* __restrict__ WT2,
                                              int nbE) {
    const int b = blockIdx.x;
    if (b >= nbE) {  // weight transpose+convert lane
        int j = (b - nbE) * 256 + threadIdx.x;  // 16384 total
        int k = j >> 7, nn = j & 127;
        WT1[nn * 128 + k] = f2bf(W1[k * 128 + nn]);
        WT2[nn * 128 + k] = f2bf(W2[k * 128 + nn]);
        return;
    }
    int i = b * 256 + threadIdx.x;
    if (i < e) {
        int d = dst[i];
        int r = b & 7;
        u64 add = (1ULL << 44) + (u64)(ew[i] * 4294967296.0f);
        u64 old = atomicAdd(&packed[(size_t)r * nNodes + d], add);
        rank[i] = (int)(old >> 44);
    }
}

// ---------------------------------------------------------------------------
// Scan pass 1 with fused decode: reads the 8 replicas, emits
//   dinv[i]  = rsqrt(1 + total_ewsum * 2^-32)
//   bases[i] = per-replica exclusive offsets (8 x 8-bit packed; field r at
//              shift 8r = sum of counts of replicas < r)
//   out[]    = per-1024-chunk local exclusive scan of total counts
//   sums[]   = chunk totals.
// ---------------------------------------------------------------------------
__global__ __launch_bounds__(256) void k_scan1(const u64* __restrict__ packed,
                                               float* __restrict__ dinv,
                                               u64* __restrict__ bases,
                                               int* __restrict__ out,
                                               int* __restrict__ sums, int nNodes) {
    __shared__ int s[256];
    const int t = threadIdx.x;
    const int base = blockIdx.x * 1024 + t * 4;
    const int n = nNodes + 1;  // scan domain: N counts + trailing 0
    int v[4];
    #pragma unroll
    for (int u = 0; u < 4; ++u) {
        int idx = base + u;
        int c = 0;
        if (idx < nNodes) {
            const u64 mask = (1ULL << 44) - 1;
            u64 ssum = 0;
            u64 bs = 0;
            uint32 cum = 0;
            #pragma unroll
            for (int r = 0; r < 8; ++r) {
                u64 pv = packed[(size_t)r * nNodes + idx];
                bs |= (u64)cum << (8 * r);  // field 0 = 0
                cum += (uint32)(pv >> 44);
                ssum += (pv & mask);
            }
            c = (int)cum;
            float deg = 1.0f + (float)ssum * (1.0f / 4294967296.0f);
            dinv[idx] = rsqrtf(deg);
            bases[idx] = bs;
        }
        v[u] = c;
    }
    s[t] = v[0] + v[1] + v[2] + v[3];
    __syncthreads();
    #pragma unroll
    for (int off = 1; off < 256; off <<= 1) {
        int x = (t >= off) ? s[t - off] : 0;
        __syncthreads();
        s[t] += x;
        __syncthreads();
    }
    if (t == 255) sums[blockIdx.x] = s[255];
    int e = (t == 0) ? 0 : s[t - 1];
    if (base + 0 < n) out[base + 0] = e;
    if (base + 1 < n) out[base + 1] = e + v[0];
    if (base + 2 < n) out[base + 2] = e + v[0] + v[1];
    if (base + 3 < n) out[base + 3] = e + v[0] + v[1] + v[2];
}

__global__ __launch_bounds__(256) void k_scan2(int* __restrict__ sums, int g) {
    __shared__ int s[256];
    const int t = threadIdx.x;
    s[t] = (t < g) ? sums[t] : 0;
    __syncthreads();
    #pragma unroll
    for (int off = 1; off < 256; off <<= 1) {
        int x = (t >= off) ? s[t - off] : 0;
        __syncthreads();
        s[t] += x;
        __syncthreads();
    }
    if (t < g) sums[t] = (t == 0) ? 0 : s[t - 1];  // exclusive
}

// Fill CSR (atomic-free):
//   pos = rowptr_local[d] + csums[d>>10] + base_replica(d, r) + rank[e].
__global__ __launch_bounds__(256) void k_fill(const int* __restrict__ src,
                                              const int* __restrict__ dst,
                                              const float* __restrict__ ew,
                                              const float* __restrict__ dinv,
                                              const int* __restrict__ rowptr,
                                              const int* __restrict__ csums,
                                              const u64* __restrict__ bases,
                                              const int* __restrict__ rank,
                                              float2* __restrict__ csr, int e) {
    int i = blockIdx.x * 256 + threadIdx.x;
    if (i < e) {
        int s = src[i], d = dst[i];
        int r = blockIdx.x & 7;  // must match k_hist's replica map
        float nrm = dinv[s] * ew[i] * dinv[d];
        int pos = rowptr[d] + csums[d >> 10]
                + (int)((bases[d] >> (8 * r)) & 0xFF) + rank[i];
        csr[pos] = make_float2(__int_as_float(s), nrm);
    }
}

// ---------------------------------------------------------------------------
// MFMA GEMM: H[n x 128] (bf16) = A[n x 128] @ W[128 x 128].
// WT is bf16, transposed ([n][k]). 256 threads = 4 waves; each wave owns 32
// rows x 128 cols = 2 row-tiles x 8 col-tiles of 16x16, K=128 in 4 steps.
// AFP32: A is fp32 (converted inline) vs bf16.
// ---------------------------------------------------------------------------
template <int AFP32>
__global__ __launch_bounds__(256) void k_gemm(const void* __restrict__ Ap,
                                              const unsigned short* __restrict__ WT,
                                              unsigned short* __restrict__ H, int n) {
    const int lane = threadIdx.x & 63;
    const int wv   = threadIdx.x >> 6;
    const int quad = lane >> 4;
    const int l16  = lane & 15;
    const int m0   = blockIdx.x * 128 + wv * 32;
    f32x4 acc[2][8] = {};

    #pragma unroll
    for (int ks = 0; ks < 4; ++ks) {
        const int k0 = ks * 32 + quad * 8;
        bf16x8 a[2];
        #pragma unroll
        for (int rt = 0; rt < 2; ++rt) {
            int row = m0 + rt * 16 + l16;
            if (row >= n) row = n - 1;  // clamp; stores are guarded
            if (AFP32) {
                const float* Af = (const float*)Ap + (size_t)row * 128 + k0;
                float4 f0 = *(const float4*)(Af);
                float4 f1 = *(const float4*)(Af + 4);
                bf16x8 v;
                v[0] = (short)f2bf(f0.x); v[1] = (short)f2bf(f0.y);
                v[2] = (short)f2bf(f0.z); v[3] = (short)f2bf(f0.w);
                v[4] = (short)f2bf(f1.x); v[5] = (short)f2bf(f1.y);
                v[6] = (short)f2bf(f1.z); v[7] = (short)f2bf(f1.w);
                a[rt] = v;
            } else {
                const unsigned short* Ab = (const unsigned short*)Ap + (size_t)row * 128 + k0;
                a[rt] = *(const bf16x8*)Ab;
            }
        }
        #pragma unroll
        for (int ct = 0; ct < 8; ++ct) {
            bf16x8 b = *(const bf16x8*)(WT + (size_t)(ct * 16 + l16) * 128 + k0);
            acc[0][ct] = __builtin_amdgcn_mfma_f32_16x16x32_bf16(a[0], b, acc[0][ct], 0, 0, 0);
            acc[1][ct] = __builtin_amdgcn_mfma_f32_16x16x32_bf16(a[1], b, acc[1][ct], 0, 0, 0);
        }
    }

    // D layout: col = lane&15, row = quad*4 + reg  (m89-verified)
    #pragma unroll
    for (int rt = 0; rt < 2; ++rt) {
        #pragma unroll
        for (int r = 0; r < 4; ++r) {
            int row = m0 + rt * 16 + quad * 4 + r;
            if (row < n) {
                unsigned short* o = H + (size_t)row * 128 + l16;
                #pragma unroll
                for (int ct = 0; ct < 8; ++ct)
                    o[ct * 16] = f2bf(acc[rt][ct][r]);
            }
        }
    }
}

// ---------------------------------------------------------------------------
// CSR gather, quarter-wave layout: one 64-lane wave per node; each 16-lane
// quarter reads full 256 B bf16 rows as uint4 (16 B/lane). Per iteration the
// wave covers 16 edges (4 per quarter, 4 row-loads in flight). Partial sums
// combined across quarters with __shfl_xor(16/32). fp32 accumulation.
// ACT 0: relu -> bf16 row (feeds layer-2 MFMA). ACT 1: sigmoid -> fp32 row.
// ---------------------------------------------------------------------------
__device__ __forceinline__ void fma8(float* acc, uint4 u, float w) {
    float2 f;
    f = bf2_decode(u.x); acc[0] += f.x * w; acc[1] += f.y * w;
    f = bf2_decode(u.y); acc[2] += f.x * w; acc[3] += f.y * w;
    f = bf2_decode(u.z); acc[4] += f.x * w; acc[5] += f.y * w;
    f = bf2_decode(u.w); acc[6] += f.x * w; acc[7] += f.y * w;
}

template <int ACT>
__global__ __launch_bounds__(256) void k_gather(const uint4* __restrict__ Hb4,
                                                const float2* __restrict__ csr,
                                                const int* __restrict__ rowptr,
                                                const int* __restrict__ csums,
                                                const float* __restrict__ dinv,
                                                const float4* __restrict__ bias4,
                                                void* __restrict__ outp, int N) {
    int node = blockIdx.x * 4 + (threadIdx.x >> 6);
    if (node >= N) return;
    const int lane = threadIdx.x & 63;
    const int q = lane >> 4, l = lane & 15;
    const int start = rowptr[node] + csums[node >> 10];
    const int end   = rowptr[node + 1] + csums[(node + 1) >> 10];

    // self-loop (ew=1, norm=dinv^2): counted once, via quarter 0 only
    float di = dinv[node];
    float selfw = (q == 0) ? di * di : 0.0f;
    float acc[8] = {};
    fma8(acc, Hb4[(size_t)node * 16 + l], selfw);

    for (int k = start; k < end; k += 16) {  // 16 edges/iter across quarters
        float2 c[4];
        float w[4];
        uint4 u[4];
        #pragma unroll
        for (int j = 0; j < 4; ++j) {
            int ej = k + q + 4 * j;
            c[j] = csr[ej < end ? ej : end - 1];
            w[j] = (ej < end) ? c[j].y : 0.0f;
        }
        #pragma unroll
        for (int j = 0; j < 4; ++j)
            u[j] = Hb4[(size_t)__float_as_int(c[j].x) * 16 + l];
        #pragma unroll
        for (int j = 0; j < 4; ++j)
            fma8(acc, u[j], w[j]);
    }

    // combine quarters: after xor-16 and xor-32 every lane holds the total
    #pragma unroll
    for (int j = 0; j < 8; ++j) {
        acc[j] += __shfl_xor(acc[j], 16, 64);
        acc[j] += __shfl_xor(acc[j], 32, 64);
    }

    if (q == 0) {  // lanes 0..15 write the row
        float4 b0 = bias4[l * 2], b1 = bias4[l * 2 + 1];
        acc[0] += b0.x; acc[1] += b0.y; acc[2] += b0.z; acc[3] += b0.w;
        acc[4] += b1.x; acc[5] += b1.y; acc[6] += b1.z; acc[7] += b1.w;
        if (ACT == 0) {
            #pragma unroll
            for (int j = 0; j < 8; ++j) acc[j] = fmaxf(acc[j], 0.0f);
            uint4 o;
            o.x = (uint32)f2bf(acc[0]) | ((uint32)f2bf(acc[1]) << 16);
            o.y = (uint32)f2bf(acc[2]) | ((uint32)f2bf(acc[3]) << 16);
            o.z = (uint32)f2bf(acc[4]) | ((uint32)f2bf(acc[5]) << 16);
            o.w = (uint32)f2bf(acc[6]) | ((uint32)f2bf(acc[7]) << 16);
            ((uint4*)outp)[(size_t)node * 16 + l] = o;
        } else {
            #pragma unroll
            for (int j = 0; j < 8; ++j) acc[j] = 1.0f / (1.0f + expf(-acc[j]));
            float4* o4 = (float4*)outp + (size_t)node * 32 + l * 2;
            o4[0] = make_float4(acc[0], acc[1], acc[2], acc[3]);
            o4[1] = make_float4(acc[4], acc[5], acc[6], acc[7]);
        }
    }
}

extern "C" void kernel_launch(void* const* d_in, const int* in_sizes, int n_in,
                              void* d_out, int out_size, void* d_ws, size_t ws_size,
                              hipStream_t stream) {
    const float* x  = (const float*)d_in[0];
    const int*   ei = (const int*)d_in[1];
    const float* ew = (const float*)d_in[2];
    const float* W1 = (const float*)d_in[3];
    const float* b1 = (const float*)d_in[4];
    const float* W2 = (const float*)d_in[5];
    const float* b2 = (const float*)d_in[6];

    const int N = in_sizes[0] / 128;
    const int E = in_sizes[2];
    const int* src = ei;
    const int* dst = ei + E;
    float* out = (float*)d_out;

    // Workspace layout (256B-aligned slabs):
    //   dinv [N] | rowptr [N+1] | csums [1024] | bases [N u64] | WT1 | WT2
    //   | rank [E] | csr [E f2] | h [N*128 bf16] | g1 [N*128 bf16]
    //   (packed u64[8N] aliases g1: dead after k_scan1, g1 written at gather-1)
    auto align = [](size_t v) { return (v + 255) & ~(size_t)255; };
    char* p = (char*)d_ws;
    float*  dinv   = (float*)p;   p += align((size_t)N * 4);
    int*    rowptr = (int*)p;     p += align((size_t)(N + 1) * 4);
    int*    csums  = (int*)p;     p += align((size_t)1024 * 4);
    u64*    bases  = (u64*)p;     p += align((size_t)N * 8);
    unsigned short* WT1 = (unsigned short*)p; p += align((size_t)128 * 128 * 2);
    unsigned short* WT2 = (unsigned short*)p; p += align((size_t)128 * 128 * 2);
    int*    rank   = (int*)p;     p += align((size_t)E * 4);
    float2* csr    = (float2*)p;  p += align((size_t)E * 8);
    unsigned short* h  = (unsigned short*)p; p += align((size_t)N * 128 * 2);
    unsigned short* g1 = (unsigned short*)p;
    u64* packed = (u64*)g1;  // alias (8N u64 = 3.2 MB < 12.8 MB; dead after scan1)

    const int nbE = (E + 255) / 256;
    const int gScan = (N + 1 + 1023) / 1024;
    const int gGemm = (N + 127) / 128;
    const int gGath = (N + 3) / 4;

    // --- CSR + normalization build (shared by both layers) ---
    hipMemsetAsync(packed, 0, (size_t)8 * N * 8, stream);
    k_hist<<<nbE + 64, 256, 0, stream>>>(dst, ew, packed, rank, E, N,
                                         W1, W2, WT1, WT2, nbE);
    k_scan1<<<gScan, 256, 0, stream>>>(packed, dinv, bases, rowptr, csums, N);
    k_scan2<<<1, 256, 0, stream>>>(csums, gScan);
    k_fill<<<nbE, 256, 0, stream>>>(src, dst, ew, dinv, rowptr, csums, bases,
                                    rank, csr, E);

    // --- Layer 1: h = bf16(x@W1) ; g1 = bf16(relu(gather(h) + b1)) ---
    k_gemm<1><<<gGemm, 256, 0, stream>>>(x, WT1, h, N);
    k_gather<0><<<gGath, 256, 0, stream>>>((const uint4*)h, csr, rowptr, csums,
                                           dinv, (const float4*)b1, g1, N);

    // --- Layer 2: h = bf16(g1@W2) ; out = sigmoid(gather(h) + b2) ---
    k_gemm<0><<<gGemm, 256, 0, stream>>>(g1, WT2, h, N);
    k_gather<1><<<gGath, 256, 0, stream>>>((const uint4*)h, csr, rowptr, csums,
                                           dinv, (const float4*)b2, out, N);
}

// Round 11
// 218.883 us; speedup vs baseline: 3.7770x; 1.0407x over previous
//
#include <hip/hip_runtime.h>
#include <math.h>

// ---------------------------------------------------------------------------
// GCN 2-layer forward on MI355X.
// Round 11: pipeline fusion (10 -> 7 launches):
//   (1) gemm1 fused with hist in one kernel (independent work; MFMA pipe and
//       atomic/TCC pipe overlap -> time ~= max, not sum);
//   (2) scan2 folded into scan1 via last-block pattern (release-store chunk
//       totals + ACQ_REL done counter + wave shfl-scan of 49 totals);
//   (3) memset+cvtW merged into one k_init kernel.
// Replica map is now the pure function r=(i>>8)&7 (grid-shape independent).
// gemm/gather bodies unchanged from R10.
// ---------------------------------------------------------------------------

typedef unsigned int uint32;
typedef unsigned long long u64;
typedef __attribute__((ext_vector_type(8))) short bf16x8;   // 8 bf16 (4 VGPRs)
typedef __attribute__((ext_vector_type(4))) float f32x4;

__device__ __forceinline__ unsigned short f2bf(float f) {   // RNE fp32->bf16
    uint32 b = __float_as_uint(f);
    return (unsigned short)((b + 0x7FFFu + ((b >> 16) & 1u)) >> 16);
}

__device__ __forceinline__ float2 bf2_decode(uint32 u) {
    return make_float2(__uint_as_float(u << 16),
                       __uint_as_float(u & 0xFFFF0000u));
}

// ---------------------------------------------------------------------------
// MFMA GEMM body: H[n x 128] (bf16) = A[n x 128] @ W (WT bf16 transposed).
// 256 threads = 4 waves; each wave 32 rows x 128 cols (2x8 16x16 tiles),
// K=128 in 4 steps. AFP32: A is fp32 (converted inline) vs bf16.
// ---------------------------------------------------------------------------
template <int AFP32>
__device__ __forceinline__ void gemm_body(const void* __restrict__ Ap,
                                          const unsigned short* __restrict__ WT,
                                          unsigned short* __restrict__ H,
                                          int n, int tb) {
    const int lane = threadIdx.x & 63;
    const int wv   = threadIdx.x >> 6;
    const int quad = lane >> 4;
    const int l16  = lane & 15;
    const int m0   = tb * 128 + wv * 32;
    f32x4 acc[2][8] = {};

    #pragma unroll
    for (int ks = 0; ks < 4; ++ks) {
        const int k0 = ks * 32 + quad * 8;
        bf16x8 a[2];
        #pragma unroll
        for (int rt = 0; rt < 2; ++rt) {
            int row = m0 + rt * 16 + l16;
            if (row >= n) row = n - 1;  // clamp; stores are guarded
            if (AFP32) {
                const float* Af = (const float*)Ap + (size_t)row * 128 + k0;
                float4 f0 = *(const float4*)(Af);
                float4 f1 = *(const float4*)(Af + 4);
                bf16x8 v;
                v[0] = (short)f2bf(f0.x); v[1] = (short)f2bf(f0.y);
                v[2] = (short)f2bf(f0.z); v[3] = (short)f2bf(f0.w);
                v[4] = (short)f2bf(f1.x); v[5] = (short)f2bf(f1.y);
                v[6] = (short)f2bf(f1.z); v[7] = (short)f2bf(f1.w);
                a[rt] = v;
            } else {
                const unsigned short* Ab = (const unsigned short*)Ap + (size_t)row * 128 + k0;
                a[rt] = *(const bf16x8*)Ab;
            }
        }
        #pragma unroll
        for (int ct = 0; ct < 8; ++ct) {
            bf16x8 b = *(const bf16x8*)(WT + (size_t)(ct * 16 + l16) * 128 + k0);
            acc[0][ct] = __builtin_amdgcn_mfma_f32_16x16x32_bf16(a[0], b, acc[0][ct], 0, 0, 0);
            acc[1][ct] = __builtin_amdgcn_mfma_f32_16x16x32_bf16(a[1], b, acc[1][ct], 0, 0, 0);
        }
    }

    // D layout: col = lane&15, row = quad*4 + reg  (m89-verified)
    #pragma unroll
    for (int rt = 0; rt < 2; ++rt) {
        #pragma unroll
        for (int r = 0; r < 4; ++r) {
            int row = m0 + rt * 16 + quad * 4 + r;
            if (row < n) {
                unsigned short* o = H + (size_t)row * 128 + l16;
                #pragma unroll
                for (int ct = 0; ct < 8; ++ct)
                    o[ct * 16] = f2bf(acc[rt][ct][r]);
            }
        }
    }
}

// ---------------------------------------------------------------------------
// Init: zero packed[8N u64] (as uint4) + done counter; blocks [0,64) also
// transpose+convert W1/W2 to bf16 WT1/WT2.
// ---------------------------------------------------------------------------
__global__ __launch_bounds__(256) void k_init(u64* __restrict__ packed, int n4,
                                              int* __restrict__ done,
                                              const float* __restrict__ W1,
                                              const float* __restrict__ W2,
                                              unsigned short* __restrict__ WT1,
                                              unsigned short* __restrict__ WT2) {
    int idx = blockIdx.x * 256 + threadIdx.x;
    if (idx < n4) ((uint4*)packed)[idx] = make_uint4(0u, 0u, 0u, 0u);
    if (idx == 0) *done = 0;
    if (blockIdx.x < 64) {
        int j = blockIdx.x * 256 + threadIdx.x;  // 16384 total
        int k = j >> 7, nn = j & 127;
        WT1[nn * 128 + k] = f2bf(W1[k * 128 + nn]);
        WT2[nn * 128 + k] = f2bf(W2[k * 128 + nn]);
    }
}

// ---------------------------------------------------------------------------
// Fused gemm1 + hist: blocks [0,gGemm) compute h = bf16(x@W1) (MFMA pipe);
// blocks [gGemm, ...) do the 8-replica u64 histogram (atomic/TCC pipe).
// Replica r = (i>>8)&7, rank[i] = per-replica arrival order (atomic return).
// ---------------------------------------------------------------------------
__global__ __launch_bounds__(256) void k_gemm1_hist(const float* __restrict__ x,
                                                    const unsigned short* __restrict__ WT1,
                                                    unsigned short* __restrict__ h,
                                                    const int* __restrict__ dst,
                                                    const float* __restrict__ ew,
                                                    u64* __restrict__ packed,
                                                    int* __restrict__ rank,
                                                    int E, int N, int gGemm) {
    const int b = blockIdx.x;
    if (b < gGemm) {
        gemm_body<1>(x, WT1, h, N, b);
        return;
    }
    int i = (b - gGemm) * 256 + threadIdx.x;
    if (i < E) {
        int d = dst[i];
        int r = (i >> 8) & 7;
        u64 add = (1ULL << 44) + (u64)(ew[i] * 4294967296.0f);
        u64 old = atomicAdd(&packed[(size_t)r * N + d], add);
        rank[i] = (int)(old >> 44);
    }
}

// ---------------------------------------------------------------------------
// Scan (one kernel): per-1024-chunk local exclusive scan of total counts into
// rowptr, fused decode (dinv, 8x8-bit replica bases), chunk totals release-
// stored into csums; last block (done counter) wave-scans the <=64 totals
// into exclusive chunk offsets in place.
// ---------------------------------------------------------------------------
__global__ __launch_bounds__(256) void k_scan(const u64* __restrict__ packed,
                                              float* __restrict__ dinv,
                                              u64* __restrict__ bases,
                                              int* __restrict__ rowptr,
                                              int* __restrict__ csums,
                                              int* __restrict__ done, int nNodes) {
    __shared__ int s[256];
    __shared__ int lastFlag;
    const int t = threadIdx.x;
    const int base = blockIdx.x * 1024 + t * 4;
    const int n = nNodes + 1;  // scan domain: N counts + trailing 0
    int v[4];
    #pragma unroll
    for (int u = 0; u < 4; ++u) {
        int idx = base + u;
        int c = 0;
        if (idx < nNodes) {
            const u64 mask = (1ULL << 44) - 1;
            u64 ssum = 0;
            u64 bs = 0;
            uint32 cum = 0;
            #pragma unroll
            for (int r = 0; r < 8; ++r) {
                u64 pv = packed[(size_t)r * nNodes + idx];
                bs |= (u64)cum << (8 * r);  // field 0 = 0
                cum += (uint32)(pv >> 44);
                ssum += (pv & mask);
            }
            c = (int)cum;
            float deg = 1.0f + (float)ssum * (1.0f / 4294967296.0f);
            dinv[idx] = rsqrtf(deg);
            bases[idx] = bs;
        }
        v[u] = c;
    }
    s[t] = v[0] + v[1] + v[2] + v[3];
    __syncthreads();
    #pragma unroll
    for (int off = 1; off < 256; off <<= 1) {
        int x = (t >= off) ? s[t - off] : 0;
        __syncthreads();
        s[t] += x;
        __syncthreads();
    }
    if (t == 255)
        __hip_atomic_store(&csums[blockIdx.x], s[255], __ATOMIC_RELEASE,
                           __HIP_MEMORY_SCOPE_AGENT);
    int e = (t == 0) ? 0 : s[t - 1];
    if (base + 0 < n) rowptr[base + 0] = e;
    if (base + 1 < n) rowptr[base + 1] = e + v[0];
    if (base + 2 < n) rowptr[base + 2] = e + v[0] + v[1];
    if (base + 3 < n) rowptr[base + 3] = e + v[0] + v[1] + v[2];

    // last-block: exclusive scan of the gridDim.x (<=64) chunk totals
    __syncthreads();  // all stores issued (incl. t255's release store)
    if (t == 0) {
        int prev = __hip_atomic_fetch_add(done, 1, __ATOMIC_ACQ_REL,
                                          __HIP_MEMORY_SCOPE_AGENT);
        lastFlag = (prev == (int)gridDim.x - 1);
    }
    __syncthreads();
    if (lastFlag && t < 64) {
        int g = (int)gridDim.x;
        int orig = (t < g) ? __hip_atomic_load(&csums[t], __ATOMIC_ACQUIRE,
                                               __HIP_MEMORY_SCOPE_AGENT)
                           : 0;
        int vv = orig;
        #pragma unroll
        for (int off = 1; off < 64; off <<= 1) {
            int y = __shfl_up(vv, off, 64);
            if (t >= off) vv += y;
        }
        if (t < g) csums[t] = vv - orig;  // exclusive chunk offset
    }
}

// Fill CSR (atomic-free):
//   pos = rowptr_local[d] + csums[d>>10] + base_replica(d, r) + rank[e].
__global__ __launch_bounds__(256) void k_fill(const int* __restrict__ src,
                                              const int* __restrict__ dst,
                                              const float* __restrict__ ew,
                                              const float* __restrict__ dinv,
                                              const int* __restrict__ rowptr,
                                              const int* __restrict__ csums,
                                              const u64* __restrict__ bases,
                                              const int* __restrict__ rank,
                                              float2* __restrict__ csr, int e) {
    int i = blockIdx.x * 256 + threadIdx.x;
    if (i < e) {
        int s = src[i], d = dst[i];
        int r = (i >> 8) & 7;  // must match k_gemm1_hist's replica map
        float nrm = dinv[s] * ew[i] * dinv[d];
        int pos = rowptr[d] + csums[d >> 10]
                + (int)((bases[d] >> (8 * r)) & 0xFF) + rank[i];
        csr[pos] = make_float2(__int_as_float(s), nrm);
    }
}

// Standalone GEMM kernel (layer 2, bf16 input).
template <int AFP32>
__global__ __launch_bounds__(256) void k_gemm(const void* __restrict__ Ap,
                                              const unsigned short* __restrict__ WT,
                                              unsigned short* __restrict__ H, int n) {
    gemm_body<AFP32>(Ap, WT, H, n, blockIdx.x);
}

// ---------------------------------------------------------------------------
// CSR gather, quarter-wave layout: one 64-lane wave per node; each 16-lane
// quarter reads full 256 B bf16 rows as uint4 (16 B/lane). Per iteration the
// wave covers 16 edges (4 per quarter, 4 row-loads in flight). Partial sums
// combined across quarters with __shfl_xor(16/32). fp32 accumulation.
// ACT 0: relu -> bf16 row (feeds layer-2 MFMA). ACT 1: sigmoid -> fp32 row.
// ---------------------------------------------------------------------------
__device__ __forceinline__ void fma8(float* acc, uint4 u, float w) {
    float2 f;
    f = bf2_decode(u.x); acc[0] += f.x * w; acc[1] += f.y * w;
    f = bf2_decode(u.y); acc[2] += f.x * w; acc[3] += f.y * w;
    f = bf2_decode(u.z); acc[4] += f.x * w; acc[5] += f.y * w;
    f = bf2_decode(u.w); acc[6] += f.x * w; acc[7] += f.y * w;
}

template <int ACT>
__global__ __launch_bounds__(256) void k_gather(const uint4* __restrict__ Hb4,
                                                const float2* __restrict__ csr,
                                                const int* __restrict__ rowptr,
                                                const int* __restrict__ csums,
                                                const float* __restrict__ dinv,
                                                const float4* __restrict__ bias4,
                                                void* __restrict__ outp, int N) {
    int node = blockIdx.x * 4 + (threadIdx.x >> 6);
    if (node >= N) return;
    const int lane = threadIdx.x & 63;
    const int q = lane >> 4, l = lane & 15;
    const int start = rowptr[node] + csums[node >> 10];
    const int end   = rowptr[node + 1] + csums[(node + 1) >> 10];

    // self-loop (ew=1, norm=dinv^2): counted once, via quarter 0 only
    float di = dinv[node];
    float selfw = (q == 0) ? di * di : 0.0f;
    float acc[8] = {};
    fma8(acc, Hb4[(size_t)node * 16 + l], selfw);

    for (int k = start; k < end; k += 16) {  // 16 edges/iter across quarters
        float2 c[4];
        float w[4];
        uint4 u[4];
        #pragma unroll
        for (int j = 0; j < 4; ++j) {
            int ej = k + q + 4 * j;
            c[j] = csr[ej < end ? ej : end - 1];
            w[j] = (ej < end) ? c[j].y : 0.0f;
        }
        #pragma unroll
        for (int j = 0; j < 4; ++j)
            u[j] = Hb4[(size_t)__float_as_int(c[j].x) * 16 + l];
        #pragma unroll
        for (int j = 0; j < 4; ++j)
            fma8(acc, u[j], w[j]);
    }

    // combine quarters: after xor-16 and xor-32 every lane holds the total
    #pragma unroll
    for (int j = 0; j < 8; ++j) {
        acc[j] += __shfl_xor(acc[j], 16, 64);
        acc[j] += __shfl_xor(acc[j], 32, 64);
    }

    if (q == 0) {  // lanes 0..15 write the row
        float4 b0 = bias4[l * 2], b1 = bias4[l * 2 + 1];
        acc[0] += b0.x; acc[1] += b0.y; acc[2] += b0.z; acc[3] += b0.w;
        acc[4] += b1.x; acc[5] += b1.y; acc[6] += b1.z; acc[7] += b1.w;
        if (ACT == 0) {
            #pragma unroll
            for (int j = 0; j < 8; ++j) acc[j] = fmaxf(acc[j], 0.0f);
            uint4 o;
            o.x = (uint32)f2bf(acc[0]) | ((uint32)f2bf(acc[1]) << 16);
            o.y = (uint32)f2bf(acc[2]) | ((uint32)f2bf(acc[3]) << 16);
            o.z = (uint32)f2bf(acc[4]) | ((uint32)f2bf(acc[5]) << 16);
            o.w = (uint32)f2bf(acc[6]) | ((uint32)f2bf(acc[7]) << 16);
            ((uint4*)outp)[(size_t)node * 16 + l] = o;
        } else {
            #pragma unroll
            for (int j = 0; j < 8; ++j) acc[j] = 1.0f / (1.0f + expf(-acc[j]));
            float4* o4 = (float4*)outp + (size_t)node * 32 + l * 2;
            o4[0] = make_float4(acc[0], acc[1], acc[2], acc[3]);
            o4[1] = make_float4(acc[4], acc[5], acc[6], acc[7]);
        }
    }
}

extern "C" void kernel_launch(void* const* d_in, const int* in_sizes, int n_in,
                              void* d_out, int out_size, void* d_ws, size_t ws_size,
                              hipStream_t stream) {
    const float* x  = (const float*)d_in[0];
    const int*   ei = (const int*)d_in[1];
    const float* ew = (const float*)d_in[2];
    const float* W1 = (const float*)d_in[3];
    const float* b1 = (const float*)d_in[4];
    const float* W2 = (const float*)d_in[5];
    const float* b2 = (const float*)d_in[6];

    const int N = in_sizes[0] / 128;
    const int E = in_sizes[2];
    const int* src = ei;
    const int* dst = ei + E;
    float* out = (float*)d_out;

    // Workspace layout (256B-aligned slabs):
    //   dinv [N] | rowptr [N+1] | csums [1024] | done [1] | bases [N u64]
    //   | WT1 | WT2 | rank [E] | csr [E f2] | h [N*128 bf16] | g1 [N*128 bf16]
    //   (packed u64[8N] aliases g1: dead after k_scan, g1 written at gather-1)
    auto align = [](size_t v) { return (v + 255) & ~(size_t)255; };
    char* p = (char*)d_ws;
    float*  dinv   = (float*)p;   p += align((size_t)N * 4);
    int*    rowptr = (int*)p;     p += align((size_t)(N + 1) * 4);
    int*    csums  = (int*)p;     p += align((size_t)1024 * 4);
    int*    done   = (int*)p;     p += align((size_t)256);
    u64*    bases  = (u64*)p;     p += align((size_t)N * 8);
    unsigned short* WT1 = (unsigned short*)p; p += align((size_t)128 * 128 * 2);
    unsigned short* WT2 = (unsigned short*)p; p += align((size_t)128 * 128 * 2);
    int*    rank   = (int*)p;     p += align((size_t)E * 4);
    float2* csr    = (float2*)p;  p += align((size_t)E * 8);
    unsigned short* h  = (unsigned short*)p; p += align((size_t)N * 128 * 2);
    unsigned short* g1 = (unsigned short*)p;
    u64* packed = (u64*)g1;  // alias (8N u64 = 3.2 MB < 12.8 MB; dead after scan)

    const int nbE = (E + 255) / 256;
    const int gScan = (N + 1 + 1023) / 1024;   // 49 for N=50000 (<=64 required)
    const int gGemm = (N + 127) / 128;
    const int gGath = (N + 3) / 4;
    const int n4 = N * 4;                      // 8N u64 = 4N uint4
    const int gInit = ((n4 + 255) / 256) < 64 ? 64 : ((n4 + 255) / 256);

    // --- Build (+ layer-1 GEMM overlapped with hist) ---
    k_init<<<gInit, 256, 0, stream>>>(packed, n4, done, W1, W2, WT1, WT2);
    k_gemm1_hist<<<gGemm + nbE, 256, 0, stream>>>(x, WT1, h, dst, ew, packed,
                                                  rank, E, N, gGemm);
    k_scan<<<gScan, 256, 0, stream>>>(packed, dinv, bases, rowptr, csums, done, N);
    k_fill<<<nbE, 256, 0, stream>>>(src, dst, ew, dinv, rowptr, csums, bases,
                                    rank, csr, E);

    // --- Layer 1 aggregation: g1 = bf16(relu(gather(h) + b1)) ---
    k_gather<0><<<gGath, 256, 0, stream>>>((const uint4*)h, csr, rowptr, csums,
                                           dinv, (const float4*)b1, g1, N);

    // --- Layer 2: h = bf16(g1@W2) ; out = sigmoid(gather(h) + b2) ---
    k_gemm<0><<<gGemm, 256, 0, stream>>>(g1, WT2, h, N);
    k_gather<1><<<gGath, 256, 0, stream>>>((const uint4*)h, csr, rowptr, csums,
                                           dinv, (const float4*)b2, out, N);
}

// Round 12
// 207.802 us; speedup vs baseline: 3.9784x; 1.0533x over previous
//
#include <hip/hip_runtime.h>
#include <math.h>

// ---------------------------------------------------------------------------
// GCN 2-layer forward on MI355X.
// Round 12: layer-1 h table stored as fp8 e4m3 (HW cvt_pk encode/decode).
// Halves gather-0's random-read footprint (12.8 -> 6.4 MB table, 256 -> 128 B
// rows). Layer-2 h2 stays bf16: layer-1 fp8 noise is attenuated ~0.036x
// downstream (gemm2 0.29 x agg 0.5 x sigmoid 0.25), layer-2 noise would hit
// pre-sigmoid directly. Everything else unchanged from R11.
// ---------------------------------------------------------------------------

typedef unsigned int uint32;
typedef unsigned long long u64;
typedef __attribute__((ext_vector_type(8))) short bf16x8;   // 8 bf16 (4 VGPRs)
typedef __attribute__((ext_vector_type(4))) float f32x4;
typedef __attribute__((ext_vector_type(2))) float f32x2;

__device__ __forceinline__ unsigned short f2bf(float f) {   // RNE fp32->bf16
    uint32 b = __float_as_uint(f);
    return (unsigned short)((b + 0x7FFFu + ((b >> 16) & 1u)) >> 16);
}

__device__ __forceinline__ float2 bf2_decode(uint32 u) {
    return make_float2(__uint_as_float(u << 16),
                       __uint_as_float(u & 0xFFFF0000u));
}

// ---------------------------------------------------------------------------
// MFMA GEMM body: H[n x 128] = A[n x 128] @ W (WT bf16 transposed).
// 256 threads = 4 waves; each wave 32 rows x 128 cols (2x8 16x16 tiles),
// K=128 in 4 steps. AFP32: A fp32 (converted inline) vs bf16.
// OUTFP8: D written as fp8 e4m3 bytes vs bf16.
// ---------------------------------------------------------------------------
template <int AFP32, int OUTFP8>
__device__ __forceinline__ void gemm_body(const void* __restrict__ Ap,
                                          const unsigned short* __restrict__ WT,
                                          void* __restrict__ H,
                                          int n, int tb) {
    const int lane = threadIdx.x & 63;
    const int wv   = threadIdx.x >> 6;
    const int quad = lane >> 4;
    const int l16  = lane & 15;
    const int m0   = tb * 128 + wv * 32;
    f32x4 acc[2][8] = {};

    #pragma unroll
    for (int ks = 0; ks < 4; ++ks) {
        const int k0 = ks * 32 + quad * 8;
        bf16x8 a[2];
        #pragma unroll
        for (int rt = 0; rt < 2; ++rt) {
            int row = m0 + rt * 16 + l16;
            if (row >= n) row = n - 1;  // clamp; stores are guarded
            if (AFP32) {
                const float* Af = (const float*)Ap + (size_t)row * 128 + k0;
                float4 f0 = *(const float4*)(Af);
                float4 f1 = *(const float4*)(Af + 4);
                bf16x8 v;
                v[0] = (short)f2bf(f0.x); v[1] = (short)f2bf(f0.y);
                v[2] = (short)f2bf(f0.z); v[3] = (short)f2bf(f0.w);
                v[4] = (short)f2bf(f1.x); v[5] = (short)f2bf(f1.y);
                v[6] = (short)f2bf(f1.z); v[7] = (short)f2bf(f1.w);
                a[rt] = v;
            } else {
                const unsigned short* Ab = (const unsigned short*)Ap + (size_t)row * 128 + k0;
                a[rt] = *(const bf16x8*)Ab;
            }
        }
        #pragma unroll
        for (int ct = 0; ct < 8; ++ct) {
            bf16x8 b = *(const bf16x8*)(WT + (size_t)(ct * 16 + l16) * 128 + k0);
            acc[0][ct] = __builtin_amdgcn_mfma_f32_16x16x32_bf16(a[0], b, acc[0][ct], 0, 0, 0);
            acc[1][ct] = __builtin_amdgcn_mfma_f32_16x16x32_bf16(a[1], b, acc[1][ct], 0, 0, 0);
        }
    }

    // D layout: col = lane&15, row = quad*4 + reg  (m89-verified)
    #pragma unroll
    for (int rt = 0; rt < 2; ++rt) {
        #pragma unroll
        for (int r = 0; r < 4; ++r) {
            int row = m0 + rt * 16 + quad * 4 + r;
            if (row < n) {
                if (OUTFP8) {
                    unsigned char* o = (unsigned char*)H + (size_t)row * 128 + l16;
                    #pragma unroll
                    for (int cp = 0; cp < 4; ++cp) {
                        int pk = __builtin_amdgcn_cvt_pk_fp8_f32(
                            acc[rt][2 * cp][r], acc[rt][2 * cp + 1][r], 0, false);
                        o[(2 * cp) * 16]     = (unsigned char)(pk & 0xFF);
                        o[(2 * cp + 1) * 16] = (unsigned char)((pk >> 8) & 0xFF);
                    }
                } else {
                    unsigned short* o = (unsigned short*)H + (size_t)row * 128 + l16;
                    #pragma unroll
                    for (int ct = 0; ct < 8; ++ct)
                        o[ct * 16] = f2bf(acc[rt][ct][r]);
                }
            }
        }
    }
}

// ---------------------------------------------------------------------------
// Init: zero packed[8N u64] (as uint4) + done counter; blocks [0,64) also
// transpose+convert W1/W2 to bf16 WT1/WT2.
// ---------------------------------------------------------------------------
__global__ __launch_bounds__(256) void k_init(u64* __restrict__ packed, int n4,
                                              int* __restrict__ done,
                                              const float* __restrict__ W1,
                                              const float* __restrict__ W2,
                                              unsigned short* __restrict__ WT1,
                                              unsigned short* __restrict__ WT2) {
    int idx = blockIdx.x * 256 + threadIdx.x;
    if (idx < n4) ((uint4*)packed)[idx] = make_uint4(0u, 0u, 0u, 0u);
    if (idx == 0) *done = 0;
    if (blockIdx.x < 64) {
        int j = blockIdx.x * 256 + threadIdx.x;  // 16384 total
        int k = j >> 7, nn = j & 127;
        WT1[nn * 128 + k] = f2bf(W1[k * 128 + nn]);
        WT2[nn * 128 + k] = f2bf(W2[k * 128 + nn]);
    }
}

// ---------------------------------------------------------------------------
// Fused gemm1 + hist: blocks [0,gGemm) compute h8 = fp8(x@W1) (MFMA pipe);
// blocks [gGemm, ...) do the 8-replica u64 histogram (atomic/TCC pipe).
// Replica r = (i>>8)&7, rank[i] = per-replica arrival order (atomic return).
// ---------------------------------------------------------------------------
__global__ __launch_bounds__(256) void k_gemm1_hist(const float* __restrict__ x,
                                                    const unsigned short* __restrict__ WT1,
                                                    unsigned char* __restrict__ h8,
                                                    const int* __restrict__ dst,
                                                    const float* __restrict__ ew,
                                                    u64* __restrict__ packed,
                                                    int* __restrict__ rank,
                                                    int E, int N, int gGemm) {
    const int b = blockIdx.x;
    if (b < gGemm) {
        gemm_body<1, 1>(x, WT1, h8, N, b);
        return;
    }
    int i = (b - gGemm) * 256 + threadIdx.x;
    if (i < E) {
        int d = dst[i];
        int r = (i >> 8) & 7;
        u64 add = (1ULL << 44) + (u64)(ew[i] * 4294967296.0f);
        u64 old = atomicAdd(&packed[(size_t)r * N + d], add);
        rank[i] = (int)(old >> 44);
    }
}

// ---------------------------------------------------------------------------
// Scan (one kernel): per-1024-chunk local exclusive scan of total counts into
// rowptr, fused decode (dinv, 8x8-bit replica bases), chunk totals release-
// stored into csums; last block (done counter) wave-scans the <=64 totals
// into exclusive chunk offsets in place.
// ---------------------------------------------------------------------------
__global__ __launch_bounds__(256) void k_scan(const u64* __restrict__ packed,
                                              float* __restrict__ dinv,
                                              u64* __restrict__ bases,
                                              int* __restrict__ rowptr,
                                              int* __restrict__ csums,
                                              int* __restrict__ done, int nNodes) {
    __shared__ int s[256];
    __shared__ int lastFlag;
    const int t = threadIdx.x;
    const int base = blockIdx.x * 1024 + t * 4;
    const int n = nNodes + 1;  // scan domain: N counts + trailing 0
    int v[4];
    #pragma unroll
    for (int u = 0; u < 4; ++u) {
        int idx = base + u;
        int c = 0;
        if (idx < nNodes) {
            const u64 mask = (1ULL << 44) - 1;
            u64 ssum = 0;
            u64 bs = 0;
            uint32 cum = 0;
            #pragma unroll
            for (int r = 0; r < 8; ++r) {
                u64 pv = packed[(size_t)r * nNodes + idx];
                bs |= (u64)cum << (8 * r);  // field 0 = 0
                cum += (uint32)(pv >> 44);
                ssum += (pv & mask);
            }
            c = (int)cum;
            float deg = 1.0f + (float)ssum * (1.0f / 4294967296.0f);
            dinv[idx] = rsqrtf(deg);
            bases[idx] = bs;
        }
        v[u] = c;
    }
    s[t] = v[0] + v[1] + v[2] + v[3];
    __syncthreads();
    #pragma unroll
    for (int off = 1; off < 256; off <<= 1) {
        int x = (t >= off) ? s[t - off] : 0;
        __syncthreads();
        s[t] += x;
        __syncthreads();
    }
    if (t == 255)
        __hip_atomic_store(&csums[blockIdx.x], s[255], __ATOMIC_RELEASE,
                           __HIP_MEMORY_SCOPE_AGENT);
    int e = (t == 0) ? 0 : s[t - 1];
    if (base + 0 < n) rowptr[base + 0] = e;
    if (base + 1 < n) rowptr[base + 1] = e + v[0];
    if (base + 2 < n) rowptr[base + 2] = e + v[0] + v[1];
    if (base + 3 < n) rowptr[base + 3] = e + v[0] + v[1] + v[2];

    // last-block: exclusive scan of the gridDim.x (<=64) chunk totals
    __syncthreads();  // all stores issued (incl. t255's release store)
    if (t == 0) {
        int prev = __hip_atomic_fetch_add(done, 1, __ATOMIC_ACQ_REL,
                                          __HIP_MEMORY_SCOPE_AGENT);
        lastFlag = (prev == (int)gridDim.x - 1);
    }
    __syncthreads();
    if (lastFlag && t < 64) {
        int g = (int)gridDim.x;
        int orig = (t < g) ? __hip_atomic_load(&csums[t], __ATOMIC_ACQUIRE,
                                               __HIP_MEMORY_SCOPE_AGENT)
                           : 0;
        int vv = orig;
        #pragma unroll
        for (int off = 1; off < 64; off <<= 1) {
            int y = __shfl_up(vv, off, 64);
            if (t >= off) vv += y;
        }
        if (t < g) csums[t] = vv - orig;  // exclusive chunk offset
    }
}

// Fill CSR (atomic-free):
//   pos = rowptr_local[d] + csums[d>>10] + base_replica(d, r) + rank[e].
__global__ __launch_bounds__(256) void k_fill(const int* __restrict__ src,
                                              const int* __restrict__ dst,
                                              const float* __restrict__ ew,
                                              const float* __restrict__ dinv,
                                              const int* __restrict__ rowptr,
                                              const int* __restrict__ csums,
                                              const u64* __restrict__ bases,
                                              const int* __restrict__ rank,
                                              float2* __restrict__ csr, int e) {
    int i = blockIdx.x * 256 + threadIdx.x;
    if (i < e) {
        int s = src[i], d = dst[i];
        int r = (i >> 8) & 7;  // must match k_gemm1_hist's replica map
        float nrm = dinv[s] * ew[i] * dinv[d];
        int pos = rowptr[d] + csums[d >> 10]
                + (int)((bases[d] >> (8 * r)) & 0xFF) + rank[i];
        csr[pos] = make_float2(__int_as_float(s), nrm);
    }
}

// Standalone GEMM kernel (layer 2: bf16 in, bf16 out).
__global__ __launch_bounds__(256) void k_gemm2(const unsigned short* __restrict__ Ap,
                                               const unsigned short* __restrict__ WT,
                                               unsigned short* __restrict__ H, int n) {
    gemm_body<0, 0>(Ap, WT, H, n, blockIdx.x);
}

// ---------------------------------------------------------------------------
// CSR gather, quarter-wave layout: one 64-lane wave per node; each 16-lane
// quarter reads a full feature row (INFP8: uint2 = 8 fp8/lane, 128 B row;
// else uint4 = 8 bf16/lane, 256 B row). Per iteration the wave covers 16
// edges (4 per quarter, 4 row-loads in flight). Partial sums combined across
// quarters with __shfl_xor(16/32). fp32 accumulation.
// ACT 0: relu -> bf16 row (feeds layer-2 MFMA). ACT 1: sigmoid -> fp32 row.
// ---------------------------------------------------------------------------
__device__ __forceinline__ void fma8_bf(float* acc, uint4 u, float w) {
    float2 f;
    f = bf2_decode(u.x); acc[0] += f.x * w; acc[1] += f.y * w;
    f = bf2_decode(u.y); acc[2] += f.x * w; acc[3] += f.y * w;
    f = bf2_decode(u.z); acc[4] += f.x * w; acc[5] += f.y * w;
    f = bf2_decode(u.w); acc[6] += f.x * w; acc[7] += f.y * w;
}

__device__ __forceinline__ void fma8_f8(float* acc, uint2 u, float w) {
    f32x2 f;
    f = __builtin_amdgcn_cvt_pk_f32_fp8((int)u.x, false);
    acc[0] += f[0] * w; acc[1] += f[1] * w;
    f = __builtin_amdgcn_cvt_pk_f32_fp8((int)u.x, true);
    acc[2] += f[0] * w; acc[3] += f[1] * w;
    f = __builtin_amdgcn_cvt_pk_f32_fp8((int)u.y, false);
    acc[4] += f[0] * w; acc[5] += f[1] * w;
    f = __builtin_amdgcn_cvt_pk_f32_fp8((int)u.y, true);
    acc[6] += f[0] * w; acc[7] += f[1] * w;
}

template <int INFP8, int ACT>
__global__ __launch_bounds__(256) void k_gather(const void* __restrict__ Hp,
                                                const float2* __restrict__ csr,
                                                const int* __restrict__ rowptr,
                                                const int* __restrict__ csums,
                                                const float* __restrict__ dinv,
                                                const float4* __restrict__ bias4,
                                                void* __restrict__ outp, int N) {
    int node = blockIdx.x * 4 + (threadIdx.x >> 6);
    if (node >= N) return;
    const int lane = threadIdx.x & 63;
    const int q = lane >> 4, l = lane & 15;
    const int start = rowptr[node] + csums[node >> 10];
    const int end   = rowptr[node + 1] + csums[(node + 1) >> 10];

    const uint2* H2 = (const uint2*)Hp;   // fp8 rows: 16 x 8 B
    const uint4* H4 = (const uint4*)Hp;   // bf16 rows: 16 x 16 B

    // self-loop (ew=1, norm=dinv^2): counted once, via quarter 0 only
    float di = dinv[node];
    float selfw = (q == 0) ? di * di : 0.0f;
    float acc[8] = {};
    if (INFP8) fma8_f8(acc, H2[(size_t)node * 16 + l], selfw);
    else       fma8_bf(acc, H4[(size_t)node * 16 + l], selfw);

    for (int k = start; k < end; k += 16) {  // 16 edges/iter across quarters
        float2 c[4];
        float w[4];
        #pragma unroll
        for (int j = 0; j < 4; ++j) {
            int ej = k + q + 4 * j;
            c[j] = csr[ej < end ? ej : end - 1];
            w[j] = (ej < end) ? c[j].y : 0.0f;
        }
        if (INFP8) {
            uint2 u[4];
            #pragma unroll
            for (int j = 0; j < 4; ++j)
                u[j] = H2[(size_t)__float_as_int(c[j].x) * 16 + l];
            #pragma unroll
            for (int j = 0; j < 4; ++j) fma8_f8(acc, u[j], w[j]);
        } else {
            uint4 u[4];
            #pragma unroll
            for (int j = 0; j < 4; ++j)
                u[j] = H4[(size_t)__float_as_int(c[j].x) * 16 + l];
            #pragma unroll
            for (int j = 0; j < 4; ++j) fma8_bf(acc, u[j], w[j]);
        }
    }

    // combine quarters: after xor-16 and xor-32 every lane holds the total
    #pragma unroll
    for (int j = 0; j < 8; ++j) {
        acc[j] += __shfl_xor(acc[j], 16, 64);
        acc[j] += __shfl_xor(acc[j], 32, 64);
    }

    if (q == 0) {  // lanes 0..15 write the row
        float4 b0 = bias4[l * 2], b1 = bias4[l * 2 + 1];
        acc[0] += b0.x; acc[1] += b0.y; acc[2] += b0.z; acc[3] += b0.w;
        acc[4] += b1.x; acc[5] += b1.y; acc[6] += b1.z; acc[7] += b1.w;
        if (ACT == 0) {
            #pragma unroll
            for (int j = 0; j < 8; ++j) acc[j] = fmaxf(acc[j], 0.0f);
            uint4 o;
            o.x = (uint32)f2bf(acc[0]) | ((uint32)f2bf(acc[1]) << 16);
            o.y = (uint32)f2bf(acc[2]) | ((uint32)f2bf(acc[3]) << 16);
            o.z = (uint32)f2bf(acc[4]) | ((uint32)f2bf(acc[5]) << 16);
            o.w = (uint32)f2bf(acc[6]) | ((uint32)f2bf(acc[7]) << 16);
            ((uint4*)outp)[(size_t)node * 16 + l] = o;
        } else {
            #pragma unroll
            for (int j = 0; j < 8; ++j) acc[j] = 1.0f / (1.0f + expf(-acc[j]));
            float4* o4 = (float4*)outp + (size_t)node * 32 + l * 2;
            o4[0] = make_float4(acc[0], acc[1], acc[2], acc[3]);
            o4[1] = make_float4(acc[4], acc[5], acc[6], acc[7]);
        }
    }
}

extern "C" void kernel_launch(void* const* d_in, const int* in_sizes, int n_in,
                              void* d_out, int out_size, void* d_ws, size_t ws_size,
                              hipStream_t stream) {
    const float* x  = (const float*)d_in[0];
    const int*   ei = (const int*)d_in[1];
    const float* ew = (const float*)d_in[2];
    const float* W1 = (const float*)d_in[3];
    const float* b1 = (const float*)d_in[4];
    const float* W2 = (const float*)d_in[5];
    const float* b2 = (const float*)d_in[6];

    const int N = in_sizes[0] / 128;
    const int E = in_sizes[2];
    const int* src = ei;
    const int* dst = ei + E;
    float* out = (float*)d_out;

    // Workspace layout (256B-aligned slabs):
    //   dinv [N] | rowptr [N+1] | csums [1024] | done | bases [N u64]
    //   | WT1 | WT2 | rank [E] | csr [E f2] | h8 [N*128 fp8]
    //   | h2 [N*128 bf16] | g1 [N*128 bf16]
    //   (packed u64[8N] aliases g1: dead after k_scan, g1 written at gather-0)
    auto align = [](size_t v) { return (v + 255) & ~(size_t)255; };
    char* p = (char*)d_ws;
    float*  dinv   = (float*)p;   p += align((size_t)N * 4);
    int*    rowptr = (int*)p;     p += align((size_t)(N + 1) * 4);
    int*    csums  = (int*)p;     p += align((size_t)1024 * 4);
    int*    done   = (int*)p;     p += align((size_t)256);
    u64*    bases  = (u64*)p;     p += align((size_t)N * 8);
    unsigned short* WT1 = (unsigned short*)p; p += align((size_t)128 * 128 * 2);
    unsigned short* WT2 = (unsigned short*)p; p += align((size_t)128 * 128 * 2);
    int*    rank   = (int*)p;     p += align((size_t)E * 4);
    float2* csr    = (float2*)p;  p += align((size_t)E * 8);
    unsigned char*  h8 = (unsigned char*)p;  p += align((size_t)N * 128);
    unsigned short* h2 = (unsigned short*)p; p += align((size_t)N * 128 * 2);
    unsigned short* g1 = (unsigned short*)p;
    u64* packed = (u64*)g1;  // alias (8N u64 = 3.2 MB < 12.8 MB; dead after scan)

    const int nbE = (E + 255) / 256;
    const int gScan = (N + 1 + 1023) / 1024;   // 49 for N=50000 (<=64 required)
    const int gGemm = (N + 127) / 128;
    const int gGath = (N + 3) / 4;
    const int n4 = N * 4;                      // 8N u64 = 4N uint4
    const int gInit = ((n4 + 255) / 256) < 64 ? 64 : ((n4 + 255) / 256);

    // --- Build (+ layer-1 GEMM overlapped with hist) ---
    k_init<<<gInit, 256, 0, stream>>>(packed, n4, done, W1, W2, WT1, WT2);
    k_gemm1_hist<<<gGemm + nbE, 256, 0, stream>>>(x, WT1, h8, dst, ew, packed,
                                                  rank, E, N, gGemm);
    k_scan<<<gScan, 256, 0, stream>>>(packed, dinv, bases, rowptr, csums, done, N);
    k_fill<<<nbE, 256, 0, stream>>>(src, dst, ew, dinv, rowptr, csums, bases,
                                    rank, csr, E);

    // --- Layer 1 aggregation: g1 = bf16(relu(gather(h8) + b1)) ---
    k_gather<1, 0><<<gGath, 256, 0, stream>>>(h8, csr, rowptr, csums,
                                              dinv, (const float4*)b1, g1, N);

    // --- Layer 2: h2 = bf16(g1@W2) ; out = sigmoid(gather(h2) + b2) ---
    k_gemm2<<<gGemm, 256, 0, stream>>>(g1, WT2, h2, N);
    k_gather<0, 1><<<gGath, 256, 0, stream>>>(h2, csr, rowptr, csums,
                                              dinv, (const float4*)b2, out, N);
}